// Round 7
// baseline (417.201 us; speedup 1.0000x reference)
//
#include <hip/hip_runtime.h>
#include <hip/hip_bf16.h>

// ---------------------------------------------------------------------------
// DHN 2-layer hom-conv GNN.
// Round 7: CSR build -> two-pass radix partition over 1024-node super-buckets.
// Pass1 runs are ~1.3KB (L2 assembles full lines; write amp 5x -> ~1.1x);
// pass2 blocks own an exclusive L2-resident region and emit final CSR
// (replaces bucket_sort). Record packs as src<<16|dst (N < 65536).
// ---------------------------------------------------------------------------

#define CAPSB 17408       // per-(map,SB) capacity: mean 16384, sigma 127 -> +8 sigma
#define CHUNK 16384       // edges per pass-1 block
#define PTHREADS 512
#define SBSHIFT 10        // 1024 nodes per super-bucket

typedef __attribute__((ext_vector_type(8))) short bf16x8;
typedef __attribute__((ext_vector_type(4))) float f32x4;

__device__ inline unsigned short f2bf(float x) {           // RNE f32 -> bf16
    union { float f; unsigned u; } c; c.f = x;
    unsigned r = (c.u + 0x7FFFu + ((c.u >> 16) & 1u)) >> 16;
    return (unsigned short)r;
}
__device__ inline float bf2f(unsigned short u) {
    union { unsigned u; float f; } c; c.u = ((unsigned)u) << 16; return c.f;
}

// ---- pack 6 weight matrices [K][64] f32 -> [K/8][64][8] bf16 frags ----
__global__ void prepack_w(const float* __restrict__ W0, const float* __restrict__ W1,
                          const float* __restrict__ W2, const float* __restrict__ W3,
                          const float* __restrict__ W4, const float* __restrict__ W5,
                          unsigned short* __restrict__ wp) {
    const int m = blockIdx.x;
    const float* W = (m == 0) ? W0 : (m == 1) ? W1 : (m == 2) ? W2
                   : (m == 3) ? W3 : (m == 4) ? W4 : W5;
    const int K = (m < 3) ? 128 : 192;
    unsigned short* o = wp + (size_t)m * 12288;
    for (int idx = threadIdx.x; idx < K * 64; idx += 256) {
        int k = idx >> 6, col = idx & 63;
        o[((k >> 3) * 64 + col) * 8 + (k & 7)] = f2bf(W[idx]);
    }
}

// ---- bf16 MFMA gemm: h[:, g*64..] = in[M,K]@Wg + bg, h bf16. ----
__global__ void gemm_mfma(const float* __restrict__ in, int M, int K,
                          const unsigned short* __restrict__ wpack,
                          const float* __restrict__ b0, const float* __restrict__ b1,
                          const float* __restrict__ b2, int mslot,
                          unsigned short* __restrict__ h) {
    __shared__ __align__(16) unsigned short Ws[12288];  // K*64 bf16, K<=192
    __shared__ __align__(16) unsigned short As[2048];   // 64 rows x 32 k, swizzled

    const int g = blockIdx.y;
    const float* bias = (g == 0) ? b0 : ((g == 1) ? b1 : b2);
    const unsigned short* wp = wpack + (size_t)(mslot + g) * 12288;

    const int t = threadIdx.x;
    for (int i = t; i < K * 32; i += 256)
        ((int*)Ws)[i] = ((const int*)wp)[i];

    const int m0   = blockIdx.x * 64;
    const int lane = t & 63;
    const int wrow = (t >> 6) * 16;

    const int arow = t >> 2;
    const int aseg = t & 3;
    const int aswz = arow * 32 + ((aseg ^ ((arow >> 1) & 3)) << 3);
    const int grow = m0 + arow;
    const float* ain = in + (size_t)grow * K + aseg * 8;

    const int lrow = wrow + (lane & 15);
    const int aoff = lrow * 32 + ((((lane >> 4)) ^ ((lrow >> 1) & 3)) << 3);
    const int kq   = lane >> 4;

    f32x4 acc[4] = {};

    const int nsteps = K >> 5;
    for (int s = 0; s < nsteps; ++s) {
        __syncthreads();
        bf16x8 av = {};
        if (grow < M) {
            float4 v0 = *reinterpret_cast<const float4*>(ain + s * 32);
            float4 v1 = *reinterpret_cast<const float4*>(ain + s * 32 + 4);
            av[0] = (short)f2bf(v0.x); av[1] = (short)f2bf(v0.y);
            av[2] = (short)f2bf(v0.z); av[3] = (short)f2bf(v0.w);
            av[4] = (short)f2bf(v1.x); av[5] = (short)f2bf(v1.y);
            av[6] = (short)f2bf(v1.z); av[7] = (short)f2bf(v1.w);
        }
        *reinterpret_cast<bf16x8*>(&As[aswz]) = av;
        __syncthreads();

        bf16x8 af = *reinterpret_cast<const bf16x8*>(&As[aoff]);
        const int kg = s * 4 + kq;
        #pragma unroll
        for (int n = 0; n < 4; ++n) {
            bf16x8 bf = *reinterpret_cast<const bf16x8*>(
                &Ws[(size_t)(kg * 64 + n * 16 + (lane & 15)) * 8]);
            acc[n] = __builtin_amdgcn_mfma_f32_16x16x32_bf16(af, bf, acc[n], 0, 0, 0);
        }
    }

    #pragma unroll
    for (int n = 0; n < 4; ++n) {
        int col = n * 16 + (lane & 15);
        float bv = bias[col];
        #pragma unroll
        for (int r = 0; r < 4; ++r) {
            int row = m0 + wrow + (lane >> 4) * 4 + r;
            if (row < M)
                h[(size_t)row * 192 + g * 64 + col] = f2bf(acc[n][r] + bv);
        }
    }
}

// ---- pass 1: coarse partition into 1024-node super-buckets ----
// grid (ceil(E/CHUNK), 6), block 512. record = src<<16 | dst.
__global__ void part_coarse(const int* __restrict__ m0, const int* __restrict__ m1,
                            const int* __restrict__ m2, const int* __restrict__ m3,
                            const int* __restrict__ m4, const int* __restrict__ m5,
                            int E, int NSB, int* __restrict__ cnt,
                            unsigned* __restrict__ p1) {
    const int m = blockIdx.y;
    const int* mp = (m == 0) ? m0 : (m == 1) ? m1 : (m == 2) ? m2
                  : (m == 3) ? m3 : (m == 4) ? m4 : m5;
    __shared__ int hist[64];
    __shared__ int base[64];
    const int c0 = blockIdx.x * CHUNK;
    const int c1 = min(c0 + CHUNK, E);
    const int t = threadIdx.x;

    if (t < NSB) hist[t] = 0;
    __syncthreads();
    for (int e = c0 + t; e < c1; e += PTHREADS)
        atomicAdd(&hist[mp[e] >> SBSHIFT], 1);
    __syncthreads();
    if (t < NSB) {
        int c = hist[t];
        base[t] = (c > 0) ? atomicAdd(&cnt[m * NSB + t], c) : 0;
    }
    __syncthreads();
    if (t < NSB) hist[t] = base[t];
    __syncthreads();
    for (int e = c0 + t; e < c1; e += PTHREADS) {
        int dst = mp[e];
        unsigned src = (unsigned)mp[E + e];
        int sb = dst >> SBSHIFT;
        int pos = atomicAdd(&hist[sb], 1);
        if (pos < CAPSB)
            p1[(size_t)(m * NSB + sb) * CAPSB + pos] = (src << 16) | (unsigned)dst;
    }
}

// ---- pass 2: per-(SB,map) counting sort -> final CSR. grid (NSB,6), 512 thr ----
// Output region (CAPSB*4B = 68KB) exclusively owned -> L2-resident writes.
__global__ void sb_sort(int NSB, int N, const int* __restrict__ cnt,
                        const unsigned* __restrict__ p1,
                        unsigned* __restrict__ cols, int* __restrict__ rows) {
    const int sb = blockIdx.x;
    const int m  = blockIdx.y;
    __shared__ int bin[1024];
    __shared__ int scanbuf[512];
    const int t = threadIdx.x;
    const size_t base = (size_t)(m * NSB + sb) * CAPSB;
    const int c = min(cnt[m * NSB + sb], CAPSB);

    bin[t] = 0; bin[t + 512] = 0;
    __syncthreads();
    for (int i = t; i < c; i += 512)
        atomicAdd(&bin[p1[base + i] & 1023], 1);
    __syncthreads();

    // exclusive prefix over 1024 bins (thread t owns bins 2t, 2t+1)
    int b0 = bin[2 * t], b1 = bin[2 * t + 1];
    int tsum = b0 + b1;
    scanbuf[t] = tsum;
    __syncthreads();
    for (int off = 1; off < 512; off <<= 1) {
        int v = (t >= off) ? scanbuf[t - off] : 0;
        __syncthreads();
        scanbuf[t] += v;
        __syncthreads();
    }
    int excl = scanbuf[t] - tsum;
    bin[2 * t]     = excl;
    bin[2 * t + 1] = excl + b0;
    __syncthreads();

    // rows[m*N+n] = absolute END offset of node n's run
    for (int j = t; j < 1024; j += 512) {
        int n = (sb << SBSHIFT) + j;
        if (n < N) {
            int end = (j == 1023) ? c : bin[j + 1];
            rows[(size_t)m * N + n] = (int)(base + end);
        }
    }
    __syncthreads();

    // scatter srcs into owned global region (L2-resident)
    for (int i = t; i < c; i += 512) {
        unsigned r = p1[base + i];
        int pos = atomicAdd(&bin[r & 1023], 1);
        cols[base + pos] = r >> 16;
    }
}

// ---- wave per (node, map); lane = feature; bf16 gather, fp32 accum ----
__global__ void csr_agg(const unsigned short* __restrict__ h, const int* __restrict__ rows,
                        const unsigned* __restrict__ cols, int N, int NSB, int mapBase,
                        float* __restrict__ f) {
    const int g = blockIdx.y;
    const int m = mapBase + g;
    const int lane = threadIdx.x & 63;
    int n = (blockIdx.x * blockDim.x + threadIdx.x) >> 6;
    if (n >= N) return;
    const size_t base = (size_t)(m * NSB + (n >> SBSHIFT)) * CAPSB;
    int s = ((n & 1023) == 0) ? (int)base : rows[(size_t)m * N + n - 1];
    int e = rows[(size_t)m * N + n];
    const unsigned short* hg = h + g * 64 + lane;
    float acc = 0.f;
    int i = s;
    for (; i + 3 < e; i += 4) {
        unsigned s0 = cols[i], s1 = cols[i + 1], s2 = cols[i + 2], s3 = cols[i + 3];
        float v0 = bf2f(hg[(size_t)s0 * 192]);
        float v1 = bf2f(hg[(size_t)s1 * 192]);
        float v2 = bf2f(hg[(size_t)s2 * 192]);
        float v3 = bf2f(hg[(size_t)s3 * 192]);
        acc += (v0 + v1) + (v2 + v3);
    }
    for (; i < e; ++i) acc += bf2f(hg[(size_t)cols[i] * 192]);
    f[(size_t)n * 192 + g * 64 + lane] = fmaxf(acc, 0.f);
}

// segment-pool f (already relu'd) by sorted batch_idx.
__global__ void pool_kernel(const float* __restrict__ f, const int* __restrict__ bidx,
                            int N, float* __restrict__ pooled) {
    const int c  = threadIdx.x;          // 0..191
    const int r0 = blockIdx.x * 256;
    const int r1 = min(r0 + 256, N);
    if (r0 >= N) return;
    float acc = 0.f;
    int cur = bidx[r0];
    for (int r = r0; r < r1; ++r) {
        int b = bidx[r];
        if (b != cur) {
            atomicAdd(&pooled[(size_t)cur * 192 + c], acc);
            acc = 0.f;
            cur = b;
        }
        acc += f[(size_t)r * 192 + c];
    }
    atomicAdd(&pooled[(size_t)cur * 192 + c], acc);
}

__global__ void mlp_kernel(const float* __restrict__ pooled,
                           const float* __restrict__ A1, const float* __restrict__ ba1,
                           const float* __restrict__ A2, const float* __restrict__ ba2,
                           float* __restrict__ out) {
    __shared__ float p[192];
    __shared__ float hid[256];
    const int b = blockIdx.x;
    const int t = threadIdx.x;
    if (t < 192) p[t] = pooled[(size_t)b * 192 + t];
    __syncthreads();
    float acc = ba1[t];
    for (int k = 0; k < 192; ++k) acc += p[k] * A1[(size_t)k * 256 + t];
    hid[t] = fmaxf(acc, 0.f);
    __syncthreads();
    if (t < 10) {
        float o = ba2[t];
        for (int k = 0; k < 256; ++k) o += hid[k] * A2[(size_t)k * 10 + t];
        out[(size_t)b * 10 + t] = o;
    }
}

extern "C" void kernel_launch(void* const* d_in, const int* in_sizes, int n_in,
                              void* d_out, int out_size, void* d_ws, size_t ws_size,
                              hipStream_t stream) {
    const float* x      = (const float*)d_in[0];
    const int*   map00  = (const int*)d_in[1];
    const int*   map01  = (const int*)d_in[2];
    const int*   map02  = (const int*)d_in[3];
    const int*   map10  = (const int*)d_in[4];
    const int*   map11  = (const int*)d_in[5];
    const int*   map12  = (const int*)d_in[6];
    const int*   bidx   = (const int*)d_in[7];
    const float* W00 = (const float*)d_in[9];  const float* b00 = (const float*)d_in[10];
    const float* W01 = (const float*)d_in[11]; const float* b01 = (const float*)d_in[12];
    const float* W02 = (const float*)d_in[13]; const float* b02 = (const float*)d_in[14];
    const float* W10 = (const float*)d_in[15]; const float* b10 = (const float*)d_in[16];
    const float* W11 = (const float*)d_in[17]; const float* b11 = (const float*)d_in[18];
    const float* W12 = (const float*)d_in[19]; const float* b12 = (const float*)d_in[20];
    const float* A1  = (const float*)d_in[21]; const float* ba1 = (const float*)d_in[22];
    const float* A2  = (const float*)d_in[23]; const float* ba2 = (const float*)d_in[24];

    const int N   = in_sizes[0] / 128;
    const int E   = in_sizes[1] / 2;
    const int NSB = (N + 1023) >> SBSHIFT;     // 49 super-buckets of 1024 nodes

    unsigned short* bufH = (unsigned short*)d_ws;               // [N,192] bf16
    float*    bufF   = (float*)(bufH + (size_t)N * 192);        // [N,192] f32
    float*    pooled = bufF + (size_t)N * 192;                  // [64,192]
    int*      cnt    = (int*)(pooled + 64 * 192);               // 6*NSB
    unsigned* p1     = (unsigned*)(cnt + 6 * NSB);              // 6*NSB*CAPSB
    unsigned* cols   = p1 + (size_t)6 * NSB * CAPSB;            // 6*NSB*CAPSB
    int*      rows   = (int*)(cols + (size_t)6 * NSB * CAPSB);  // 6*N
    unsigned short* wpack = (unsigned short*)(rows + (size_t)6 * N); // 6*12288 bf16

    dim3 gemmGrid((N + 63) / 64, 3);
    dim3 p1Grid((E + CHUNK - 1) / CHUNK, 6);
    dim3 sortGrid(NSB, 6);
    dim3 aggGrid((N + 3) / 4, 3);

    // build CSR for all 6 maps + pack weights up front
    hipMemsetAsync(cnt, 0, (size_t)6 * NSB * sizeof(int), stream);
    prepack_w<<<6, 256, 0, stream>>>(W00, W01, W02, W10, W11, W12, wpack);
    part_coarse<<<p1Grid, PTHREADS, 0, stream>>>(map00, map01, map02,
                                                 map10, map11, map12,
                                                 E, NSB, cnt, p1);
    sb_sort<<<sortGrid, PTHREADS, 0, stream>>>(NSB, N, cnt, p1, cols, rows);
    // layer 0
    gemm_mfma<<<gemmGrid, 256, 0, stream>>>(x, N, 128, wpack, b00, b01, b02, 0, bufH);
    csr_agg<<<aggGrid, 256, 0, stream>>>(bufH, rows, cols, N, NSB, 0, bufF);
    // layer 1
    gemm_mfma<<<gemmGrid, 256, 0, stream>>>(bufF, N, 192, wpack, b10, b11, b12, 3, bufH);
    csr_agg<<<aggGrid, 256, 0, stream>>>(bufH, rows, cols, N, NSB, 3, bufF);
    // pool + mlp
    hipMemsetAsync(pooled, 0, 64 * 192 * sizeof(float), stream);
    pool_kernel<<<(N + 255) / 256, 192, 0, stream>>>(bufF, bidx, N, pooled);
    mlp_kernel<<<64, 256, 0, stream>>>(pooled, A1, ba1, A2, ba2, (float*)d_out);
}

// Round 8
// 346.355 us; speedup vs baseline: 1.2045x; 1.2045x over previous
//
#include <hip/hip_runtime.h>
#include <hip/hip_bf16.h>

// ---------------------------------------------------------------------------
// DHN 2-layer hom-conv GNN.
// Round 8: csr_agg was serialized on cols->gather dependency (89us x2).
//  - pad node runs to x8 with dummy src=N (zero row): branchless 8-edge groups
//  - cols as u16, one uniform uint4 load per group, prefetched 1 group ahead
//  - f buffer bf16 (csr_agg write + gemm-A/pool reads halve)
// ---------------------------------------------------------------------------

#define CAPSB 17408       // per-(map,SB) p1 capacity: mean 16384 + 8 sigma
#define CAPCOL 24576      // cols capacity: CAPSB + 1024*7 padding
#define CHUNK 16384       // edges per pass-1 block
#define PTHREADS 512
#define SBSHIFT 10        // 1024 nodes per super-bucket

typedef __attribute__((ext_vector_type(8))) short bf16x8;
typedef __attribute__((ext_vector_type(4))) float f32x4;

__device__ inline unsigned short f2bf(float x) {           // RNE f32 -> bf16
    union { float f; unsigned u; } c; c.f = x;
    unsigned r = (c.u + 0x7FFFu + ((c.u >> 16) & 1u)) >> 16;
    return (unsigned short)r;
}
__device__ inline float bf2f(unsigned short u) {
    union { unsigned u; float f; } c; c.u = ((unsigned)u) << 16; return c.f;
}

// ---- pack 6 weight matrices -> [K/8][64][8] bf16 frags; block 6 zeroes h[N] ----
__global__ void prepack_w(const float* __restrict__ W0, const float* __restrict__ W1,
                          const float* __restrict__ W2, const float* __restrict__ W3,
                          const float* __restrict__ W4, const float* __restrict__ W5,
                          unsigned short* __restrict__ wp,
                          unsigned short* __restrict__ h, int N) {
    const int m = blockIdx.x;
    if (m == 6) {                               // zero dummy row N of h
        for (int i = threadIdx.x; i < 192; i += 256) h[(size_t)N * 192 + i] = 0;
        return;
    }
    const float* W = (m == 0) ? W0 : (m == 1) ? W1 : (m == 2) ? W2
                   : (m == 3) ? W3 : (m == 4) ? W4 : W5;
    const int K = (m < 3) ? 128 : 192;
    unsigned short* o = wp + (size_t)m * 12288;
    for (int idx = threadIdx.x; idx < K * 64; idx += 256) {
        int k = idx >> 6, col = idx & 63;
        o[((k >> 3) * 64 + col) * 8 + (k & 7)] = f2bf(W[idx]);
    }
}

// ---- bf16 MFMA gemm: h[:, g*64..] = in[M,K]@Wg + bg, h bf16. ----
// INBF16=0: in is f32 (layer 0).  INBF16=1: in is bf16 (layer 1).
template <int INBF16>
__global__ void gemm_mfma(const void* __restrict__ in_, int M, int K,
                          const unsigned short* __restrict__ wpack,
                          const float* __restrict__ b0, const float* __restrict__ b1,
                          const float* __restrict__ b2, int mslot,
                          unsigned short* __restrict__ h) {
    __shared__ __align__(16) unsigned short Ws[12288];  // K*64 bf16, K<=192
    __shared__ __align__(16) unsigned short As[2048];   // 64 rows x 32 k, swizzled

    const int g = blockIdx.y;
    const float* bias = (g == 0) ? b0 : ((g == 1) ? b1 : b2);
    const unsigned short* wp = wpack + (size_t)(mslot + g) * 12288;

    const int t = threadIdx.x;
    for (int i = t; i < K * 32; i += 256)
        ((int*)Ws)[i] = ((const int*)wp)[i];

    const int m0   = blockIdx.x * 64;
    const int lane = t & 63;
    const int wrow = (t >> 6) * 16;

    const int arow = t >> 2;
    const int aseg = t & 3;
    const int aswz = arow * 32 + ((aseg ^ ((arow >> 1) & 3)) << 3);
    const int grow = m0 + arow;

    const float*          ainf = (const float*)in_ + (size_t)grow * K + aseg * 8;
    const unsigned short* ainb = (const unsigned short*)in_ + (size_t)grow * K + aseg * 8;

    const int lrow = wrow + (lane & 15);
    const int aoff = lrow * 32 + ((((lane >> 4)) ^ ((lrow >> 1) & 3)) << 3);
    const int kq   = lane >> 4;

    f32x4 acc[4] = {};

    const int nsteps = K >> 5;
    for (int s = 0; s < nsteps; ++s) {
        __syncthreads();
        bf16x8 av = {};
        if (grow < M) {
            if (INBF16) {
                av = *reinterpret_cast<const bf16x8*>(ainb + s * 32);
            } else {
                float4 v0 = *reinterpret_cast<const float4*>(ainf + s * 32);
                float4 v1 = *reinterpret_cast<const float4*>(ainf + s * 32 + 4);
                av[0] = (short)f2bf(v0.x); av[1] = (short)f2bf(v0.y);
                av[2] = (short)f2bf(v0.z); av[3] = (short)f2bf(v0.w);
                av[4] = (short)f2bf(v1.x); av[5] = (short)f2bf(v1.y);
                av[6] = (short)f2bf(v1.z); av[7] = (short)f2bf(v1.w);
            }
        }
        *reinterpret_cast<bf16x8*>(&As[aswz]) = av;
        __syncthreads();

        bf16x8 af = *reinterpret_cast<const bf16x8*>(&As[aoff]);
        const int kg = s * 4 + kq;
        #pragma unroll
        for (int n = 0; n < 4; ++n) {
            bf16x8 bfv = *reinterpret_cast<const bf16x8*>(
                &Ws[(size_t)(kg * 64 + n * 16 + (lane & 15)) * 8]);
            acc[n] = __builtin_amdgcn_mfma_f32_16x16x32_bf16(af, bfv, acc[n], 0, 0, 0);
        }
    }

    #pragma unroll
    for (int n = 0; n < 4; ++n) {
        int col = n * 16 + (lane & 15);
        float bv = bias[col];
        #pragma unroll
        for (int r = 0; r < 4; ++r) {
            int row = m0 + wrow + (lane >> 4) * 4 + r;
            if (row < M)
                h[(size_t)row * 192 + g * 64 + col] = f2bf(acc[n][r] + bv);
        }
    }
}

// ---- pass 1: coarse partition into 1024-node super-buckets ----
__global__ void part_coarse(const int* __restrict__ m0, const int* __restrict__ m1,
                            const int* __restrict__ m2, const int* __restrict__ m3,
                            const int* __restrict__ m4, const int* __restrict__ m5,
                            int E, int NSB, int* __restrict__ cnt,
                            unsigned* __restrict__ p1) {
    const int m = blockIdx.y;
    const int* mp = (m == 0) ? m0 : (m == 1) ? m1 : (m == 2) ? m2
                  : (m == 3) ? m3 : (m == 4) ? m4 : m5;
    __shared__ int hist[64];
    __shared__ int base[64];
    const int c0 = blockIdx.x * CHUNK;
    const int c1 = min(c0 + CHUNK, E);
    const int t = threadIdx.x;

    if (t < NSB) hist[t] = 0;
    __syncthreads();
    for (int e = c0 + t; e < c1; e += PTHREADS)
        atomicAdd(&hist[mp[e] >> SBSHIFT], 1);
    __syncthreads();
    if (t < NSB) {
        int c = hist[t];
        base[t] = (c > 0) ? atomicAdd(&cnt[m * NSB + t], c) : 0;
    }
    __syncthreads();
    if (t < NSB) hist[t] = base[t];
    __syncthreads();
    for (int e = c0 + t; e < c1; e += PTHREADS) {
        int dst = mp[e];
        unsigned src = (unsigned)mp[E + e];
        int sb = dst >> SBSHIFT;
        int pos = atomicAdd(&hist[sb], 1);
        if (pos < CAPSB)
            p1[(size_t)(m * NSB + sb) * CAPSB + pos] = (src << 16) | (unsigned)dst;
    }
}

// ---- pass 2: per-(SB,map) counting sort -> padded CSR (u16 cols). ----
// Node runs padded to x8 with DUMMY=N; rows[m*N+n] = padded END (absolute).
__global__ void sb_sort(int NSB, int N, const int* __restrict__ cnt,
                        const unsigned* __restrict__ p1,
                        unsigned short* __restrict__ cols, int* __restrict__ rows) {
    const int sb = blockIdx.x;
    const int m  = blockIdx.y;
    __shared__ int bin[1024];
    __shared__ int pend[1024];
    __shared__ int scanbuf[512];
    const int t = threadIdx.x;
    const size_t basep = (size_t)(m * NSB + sb) * CAPSB;
    const size_t basec = (size_t)(m * NSB + sb) * CAPCOL;
    const int c = min(cnt[m * NSB + sb], CAPSB);

    bin[t] = 0; bin[t + 512] = 0;
    __syncthreads();
    for (int i = t; i < c; i += 512)
        atomicAdd(&bin[p1[basep + i] & 1023], 1);
    __syncthreads();

    // exclusive prefix over PADDED counts (thread t owns bins 2t, 2t+1)
    int b0 = bin[2 * t], b1 = bin[2 * t + 1];
    int p0 = (b0 + 7) & ~7, p1v = (b1 + 7) & ~7;
    int tsum = p0 + p1v;
    scanbuf[t] = tsum;
    __syncthreads();
    for (int off = 1; off < 512; off <<= 1) {
        int v = (t >= off) ? scanbuf[t - off] : 0;
        __syncthreads();
        scanbuf[t] += v;
        __syncthreads();
    }
    int excl = scanbuf[t] - tsum;
    bin[2 * t]      = excl;
    pend[2 * t]     = excl + p0;
    bin[2 * t + 1]  = excl + p0;
    pend[2 * t + 1] = excl + p0 + p1v;
    __syncthreads();

    // rows[m*N+n] = absolute padded END of node n's run
    for (int j = t; j < 1024; j += 512) {
        int n = (sb << SBSHIFT) + j;
        if (n < N) rows[(size_t)m * N + n] = (int)(basec + pend[j]);
    }
    __syncthreads();

    // scatter srcs (u16) into owned region
    for (int i = t; i < c; i += 512) {
        unsigned r = p1[basep + i];
        int pos = atomicAdd(&bin[r & 1023], 1);
        cols[basec + pos] = (unsigned short)(r >> 16);
    }
    __syncthreads();

    // fill padding with DUMMY = N (zero row of h)
    for (int j = t; j < 1024; j += 512) {
        for (int k = bin[j]; k < pend[j]; ++k)
            cols[basec + k] = (unsigned short)N;
    }
}

// ---- wave per (node, map); branchless 8-edge groups, cols prefetch ----
__global__ void csr_agg(const unsigned short* __restrict__ h, const int* __restrict__ rows,
                        const unsigned short* __restrict__ cols, int N, int NSB, int mapBase,
                        unsigned short* __restrict__ f) {
    const int g = blockIdx.y;
    const int m = mapBase + g;
    const int lane = threadIdx.x & 63;
    int n = (blockIdx.x * blockDim.x + threadIdx.x) >> 6;
    if (n >= N) return;
    const size_t base = (size_t)(m * NSB + (n >> SBSHIFT)) * CAPCOL;
    int s = ((n & 1023) == 0) ? (int)base : rows[(size_t)m * N + n - 1];
    int e = rows[(size_t)m * N + n];
    const unsigned short* hg = h + g * 64 + lane;

    float acc = 0.f;
    uint4 cur = *reinterpret_cast<const uint4*>(cols + s);  // wave-uniform 16B
    for (int i = s; i < e; i += 8) {
        uint4 nxt = *reinterpret_cast<const uint4*>(cols + i + 8);  // overread: slack
        unsigned c0 = cur.x & 0xffff, c1 = cur.x >> 16;
        unsigned c2 = cur.y & 0xffff, c3 = cur.y >> 16;
        unsigned c4 = cur.z & 0xffff, c5 = cur.z >> 16;
        unsigned c6 = cur.w & 0xffff, c7 = cur.w >> 16;
        float v0 = bf2f(hg[(size_t)c0 * 192]);
        float v1 = bf2f(hg[(size_t)c1 * 192]);
        float v2 = bf2f(hg[(size_t)c2 * 192]);
        float v3 = bf2f(hg[(size_t)c3 * 192]);
        float v4 = bf2f(hg[(size_t)c4 * 192]);
        float v5 = bf2f(hg[(size_t)c5 * 192]);
        float v6 = bf2f(hg[(size_t)c6 * 192]);
        float v7 = bf2f(hg[(size_t)c7 * 192]);
        acc += ((v0 + v1) + (v2 + v3)) + ((v4 + v5) + (v6 + v7));
        cur = nxt;
    }
    f[(size_t)n * 192 + g * 64 + lane] = f2bf(fmaxf(acc, 0.f));
}

// segment-pool bf16 f (already relu'd) by sorted batch_idx, fp32 accum.
__global__ void pool_kernel(const unsigned short* __restrict__ f, const int* __restrict__ bidx,
                            int N, float* __restrict__ pooled) {
    const int c  = threadIdx.x;          // 0..191
    const int r0 = blockIdx.x * 256;
    const int r1 = min(r0 + 256, N);
    if (r0 >= N) return;
    float acc = 0.f;
    int cur = bidx[r0];
    for (int r = r0; r < r1; ++r) {
        int b = bidx[r];
        if (b != cur) {
            atomicAdd(&pooled[(size_t)cur * 192 + c], acc);
            acc = 0.f;
            cur = b;
        }
        acc += bf2f(f[(size_t)r * 192 + c]);
    }
    atomicAdd(&pooled[(size_t)cur * 192 + c], acc);
}

__global__ void mlp_kernel(const float* __restrict__ pooled,
                           const float* __restrict__ A1, const float* __restrict__ ba1,
                           const float* __restrict__ A2, const float* __restrict__ ba2,
                           float* __restrict__ out) {
    __shared__ float p[192];
    __shared__ float hid[256];
    const int b = blockIdx.x;
    const int t = threadIdx.x;
    if (t < 192) p[t] = pooled[(size_t)b * 192 + t];
    __syncthreads();
    float acc = ba1[t];
    for (int k = 0; k < 192; ++k) acc += p[k] * A1[(size_t)k * 256 + t];
    hid[t] = fmaxf(acc, 0.f);
    __syncthreads();
    if (t < 10) {
        float o = ba2[t];
        for (int k = 0; k < 256; ++k) o += hid[k] * A2[(size_t)k * 10 + t];
        out[(size_t)b * 10 + t] = o;
    }
}

extern "C" void kernel_launch(void* const* d_in, const int* in_sizes, int n_in,
                              void* d_out, int out_size, void* d_ws, size_t ws_size,
                              hipStream_t stream) {
    const float* x      = (const float*)d_in[0];
    const int*   map00  = (const int*)d_in[1];
    const int*   map01  = (const int*)d_in[2];
    const int*   map02  = (const int*)d_in[3];
    const int*   map10  = (const int*)d_in[4];
    const int*   map11  = (const int*)d_in[5];
    const int*   map12  = (const int*)d_in[6];
    const int*   bidx   = (const int*)d_in[7];
    const float* W00 = (const float*)d_in[9];  const float* b00 = (const float*)d_in[10];
    const float* W01 = (const float*)d_in[11]; const float* b01 = (const float*)d_in[12];
    const float* W02 = (const float*)d_in[13]; const float* b02 = (const float*)d_in[14];
    const float* W10 = (const float*)d_in[15]; const float* b10 = (const float*)d_in[16];
    const float* W11 = (const float*)d_in[17]; const float* b11 = (const float*)d_in[18];
    const float* W12 = (const float*)d_in[19]; const float* b12 = (const float*)d_in[20];
    const float* A1  = (const float*)d_in[21]; const float* ba1 = (const float*)d_in[22];
    const float* A2  = (const float*)d_in[23]; const float* ba2 = (const float*)d_in[24];

    const int N   = in_sizes[0] / 128;
    const int E   = in_sizes[1] / 2;
    const int NSB = (N + 1023) >> SBSHIFT;     // super-buckets of 1024 nodes

    unsigned short* bufH = (unsigned short*)d_ws;                    // [N+1,192] bf16
    unsigned short* bufF = bufH + (size_t)(N + 1) * 192;             // [N,192] bf16
    float*    pooled = (float*)(bufF + (size_t)N * 192);             // [64,192] f32
    int*      cnt    = (int*)(pooled + 64 * 192);                    // 6*NSB
    unsigned* p1     = (unsigned*)(cnt + 6 * NSB);                   // 6*NSB*CAPSB
    unsigned short* cols = (unsigned short*)(p1 + (size_t)6 * NSB * CAPSB); // +32 slack
    int*      rows   = (int*)(cols + (size_t)6 * NSB * CAPCOL + 32); // 6*N
    unsigned short* wpack = (unsigned short*)(rows + (size_t)6 * N); // 6*12288 bf16

    dim3 gemmGrid((N + 63) / 64, 3);
    dim3 p1Grid((E + CHUNK - 1) / CHUNK, 6);
    dim3 sortGrid(NSB, 6);
    dim3 aggGrid((N + 3) / 4, 3);

    // build CSR for all 6 maps + pack weights + zero dummy h row up front
    hipMemsetAsync(cnt, 0, (size_t)6 * NSB * sizeof(int), stream);
    prepack_w<<<7, 256, 0, stream>>>(W00, W01, W02, W10, W11, W12, wpack, bufH, N);
    part_coarse<<<p1Grid, PTHREADS, 0, stream>>>(map00, map01, map02,
                                                 map10, map11, map12,
                                                 E, NSB, cnt, p1);
    sb_sort<<<sortGrid, PTHREADS, 0, stream>>>(NSB, N, cnt, p1, cols, rows);
    // layer 0
    gemm_mfma<0><<<gemmGrid, 256, 0, stream>>>(x, N, 128, wpack, b00, b01, b02, 0, bufH);
    csr_agg<<<aggGrid, 256, 0, stream>>>(bufH, rows, cols, N, NSB, 0, bufF);
    // layer 1
    gemm_mfma<1><<<gemmGrid, 256, 0, stream>>>(bufF, N, 192, wpack, b10, b11, b12, 3, bufH);
    csr_agg<<<aggGrid, 256, 0, stream>>>(bufH, rows, cols, N, NSB, 3, bufF);
    // pool + mlp
    hipMemsetAsync(pooled, 0, 64 * 192 * sizeof(float), stream);
    pool_kernel<<<(N + 255) / 256, 192, 0, stream>>>(bufF, bidx, N, pooled);
    mlp_kernel<<<64, 256, 0, stream>>>(pooled, A1, ba1, A2, ba2, (float*)d_out);
}

// Round 9
// 288.985 us; speedup vs baseline: 1.4437x; 1.1985x over previous
//
#include <hip/hip_runtime.h>
#include <hip/hip_bf16.h>

// ---------------------------------------------------------------------------
// DHN 2-layer hom-conv GNN.
// Round 9: pool_kernel was latency-starved (588 waves, 6% occ, 73us for a
// 19MB read). Chunk 256 -> 32 rows: 4689 waves. Boundary atomics rise to
// ~600k total (vs 307M round-1) -- negligible.
// ---------------------------------------------------------------------------

#define CAPSB 17408       // per-(map,SB) p1 capacity: mean 16384 + 8 sigma
#define CAPCOL 24576      // cols capacity: CAPSB + 1024*7 padding
#define CHUNK 16384       // edges per pass-1 block
#define PTHREADS 512
#define SBSHIFT 10        // 1024 nodes per super-bucket
#define POOLROWS 32       // rows per pool block

typedef __attribute__((ext_vector_type(8))) short bf16x8;
typedef __attribute__((ext_vector_type(4))) float f32x4;

__device__ inline unsigned short f2bf(float x) {           // RNE f32 -> bf16
    union { float f; unsigned u; } c; c.f = x;
    unsigned r = (c.u + 0x7FFFu + ((c.u >> 16) & 1u)) >> 16;
    return (unsigned short)r;
}
__device__ inline float bf2f(unsigned short u) {
    union { unsigned u; float f; } c; c.u = ((unsigned)u) << 16; return c.f;
}

// ---- pack 6 weight matrices -> [K/8][64][8] bf16 frags; block 6 zeroes h[N] ----
__global__ void prepack_w(const float* __restrict__ W0, const float* __restrict__ W1,
                          const float* __restrict__ W2, const float* __restrict__ W3,
                          const float* __restrict__ W4, const float* __restrict__ W5,
                          unsigned short* __restrict__ wp,
                          unsigned short* __restrict__ h, int N) {
    const int m = blockIdx.x;
    if (m == 6) {                               // zero dummy row N of h
        for (int i = threadIdx.x; i < 192; i += 256) h[(size_t)N * 192 + i] = 0;
        return;
    }
    const float* W = (m == 0) ? W0 : (m == 1) ? W1 : (m == 2) ? W2
                   : (m == 3) ? W3 : (m == 4) ? W4 : W5;
    const int K = (m < 3) ? 128 : 192;
    unsigned short* o = wp + (size_t)m * 12288;
    for (int idx = threadIdx.x; idx < K * 64; idx += 256) {
        int k = idx >> 6, col = idx & 63;
        o[((k >> 3) * 64 + col) * 8 + (k & 7)] = f2bf(W[idx]);
    }
}

// ---- bf16 MFMA gemm: h[:, g*64..] = in[M,K]@Wg + bg, h bf16. ----
template <int INBF16>
__global__ void gemm_mfma(const void* __restrict__ in_, int M, int K,
                          const unsigned short* __restrict__ wpack,
                          const float* __restrict__ b0, const float* __restrict__ b1,
                          const float* __restrict__ b2, int mslot,
                          unsigned short* __restrict__ h) {
    __shared__ __align__(16) unsigned short Ws[12288];  // K*64 bf16, K<=192
    __shared__ __align__(16) unsigned short As[2048];   // 64 rows x 32 k, swizzled

    const int g = blockIdx.y;
    const float* bias = (g == 0) ? b0 : ((g == 1) ? b1 : b2);
    const unsigned short* wp = wpack + (size_t)(mslot + g) * 12288;

    const int t = threadIdx.x;
    for (int i = t; i < K * 32; i += 256)
        ((int*)Ws)[i] = ((const int*)wp)[i];

    const int m0   = blockIdx.x * 64;
    const int lane = t & 63;
    const int wrow = (t >> 6) * 16;

    const int arow = t >> 2;
    const int aseg = t & 3;
    const int aswz = arow * 32 + ((aseg ^ ((arow >> 1) & 3)) << 3);
    const int grow = m0 + arow;

    const float*          ainf = (const float*)in_ + (size_t)grow * K + aseg * 8;
    const unsigned short* ainb = (const unsigned short*)in_ + (size_t)grow * K + aseg * 8;

    const int lrow = wrow + (lane & 15);
    const int aoff = lrow * 32 + ((((lane >> 4)) ^ ((lrow >> 1) & 3)) << 3);
    const int kq   = lane >> 4;

    f32x4 acc[4] = {};

    const int nsteps = K >> 5;
    for (int s = 0; s < nsteps; ++s) {
        __syncthreads();
        bf16x8 av = {};
        if (grow < M) {
            if (INBF16) {
                av = *reinterpret_cast<const bf16x8*>(ainb + s * 32);
            } else {
                float4 v0 = *reinterpret_cast<const float4*>(ainf + s * 32);
                float4 v1 = *reinterpret_cast<const float4*>(ainf + s * 32 + 4);
                av[0] = (short)f2bf(v0.x); av[1] = (short)f2bf(v0.y);
                av[2] = (short)f2bf(v0.z); av[3] = (short)f2bf(v0.w);
                av[4] = (short)f2bf(v1.x); av[5] = (short)f2bf(v1.y);
                av[6] = (short)f2bf(v1.z); av[7] = (short)f2bf(v1.w);
            }
        }
        *reinterpret_cast<bf16x8*>(&As[aswz]) = av;
        __syncthreads();

        bf16x8 af = *reinterpret_cast<const bf16x8*>(&As[aoff]);
        const int kg = s * 4 + kq;
        #pragma unroll
        for (int n = 0; n < 4; ++n) {
            bf16x8 bfv = *reinterpret_cast<const bf16x8*>(
                &Ws[(size_t)(kg * 64 + n * 16 + (lane & 15)) * 8]);
            acc[n] = __builtin_amdgcn_mfma_f32_16x16x32_bf16(af, bfv, acc[n], 0, 0, 0);
        }
    }

    #pragma unroll
    for (int n = 0; n < 4; ++n) {
        int col = n * 16 + (lane & 15);
        float bv = bias[col];
        #pragma unroll
        for (int r = 0; r < 4; ++r) {
            int row = m0 + wrow + (lane >> 4) * 4 + r;
            if (row < M)
                h[(size_t)row * 192 + g * 64 + col] = f2bf(acc[n][r] + bv);
        }
    }
}

// ---- pass 1: coarse partition into 1024-node super-buckets ----
__global__ void part_coarse(const int* __restrict__ m0, const int* __restrict__ m1,
                            const int* __restrict__ m2, const int* __restrict__ m3,
                            const int* __restrict__ m4, const int* __restrict__ m5,
                            int E, int NSB, int* __restrict__ cnt,
                            unsigned* __restrict__ p1) {
    const int m = blockIdx.y;
    const int* mp = (m == 0) ? m0 : (m == 1) ? m1 : (m == 2) ? m2
                  : (m == 3) ? m3 : (m == 4) ? m4 : m5;
    __shared__ int hist[64];
    __shared__ int base[64];
    const int c0 = blockIdx.x * CHUNK;
    const int c1 = min(c0 + CHUNK, E);
    const int t = threadIdx.x;

    if (t < NSB) hist[t] = 0;
    __syncthreads();
    for (int e = c0 + t; e < c1; e += PTHREADS)
        atomicAdd(&hist[mp[e] >> SBSHIFT], 1);
    __syncthreads();
    if (t < NSB) {
        int c = hist[t];
        base[t] = (c > 0) ? atomicAdd(&cnt[m * NSB + t], c) : 0;
    }
    __syncthreads();
    if (t < NSB) hist[t] = base[t];
    __syncthreads();
    for (int e = c0 + t; e < c1; e += PTHREADS) {
        int dst = mp[e];
        unsigned src = (unsigned)mp[E + e];
        int sb = dst >> SBSHIFT;
        int pos = atomicAdd(&hist[sb], 1);
        if (pos < CAPSB)
            p1[(size_t)(m * NSB + sb) * CAPSB + pos] = (src << 16) | (unsigned)dst;
    }
}

// ---- pass 2: per-(SB,map) counting sort -> padded CSR (u16 cols). ----
__global__ void sb_sort(int NSB, int N, const int* __restrict__ cnt,
                        const unsigned* __restrict__ p1,
                        unsigned short* __restrict__ cols, int* __restrict__ rows) {
    const int sb = blockIdx.x;
    const int m  = blockIdx.y;
    __shared__ int bin[1024];
    __shared__ int pend[1024];
    __shared__ int scanbuf[512];
    const int t = threadIdx.x;
    const size_t basep = (size_t)(m * NSB + sb) * CAPSB;
    const size_t basec = (size_t)(m * NSB + sb) * CAPCOL;
    const int c = min(cnt[m * NSB + sb], CAPSB);

    bin[t] = 0; bin[t + 512] = 0;
    __syncthreads();
    for (int i = t; i < c; i += 512)
        atomicAdd(&bin[p1[basep + i] & 1023], 1);
    __syncthreads();

    int b0 = bin[2 * t], b1 = bin[2 * t + 1];
    int p0 = (b0 + 7) & ~7, p1v = (b1 + 7) & ~7;
    int tsum = p0 + p1v;
    scanbuf[t] = tsum;
    __syncthreads();
    for (int off = 1; off < 512; off <<= 1) {
        int v = (t >= off) ? scanbuf[t - off] : 0;
        __syncthreads();
        scanbuf[t] += v;
        __syncthreads();
    }
    int excl = scanbuf[t] - tsum;
    bin[2 * t]      = excl;
    pend[2 * t]     = excl + p0;
    bin[2 * t + 1]  = excl + p0;
    pend[2 * t + 1] = excl + p0 + p1v;
    __syncthreads();

    for (int j = t; j < 1024; j += 512) {
        int n = (sb << SBSHIFT) + j;
        if (n < N) rows[(size_t)m * N + n] = (int)(basec + pend[j]);
    }
    __syncthreads();

    for (int i = t; i < c; i += 512) {
        unsigned r = p1[basep + i];
        int pos = atomicAdd(&bin[r & 1023], 1);
        cols[basec + pos] = (unsigned short)(r >> 16);
    }
    __syncthreads();

    for (int j = t; j < 1024; j += 512) {
        for (int k = bin[j]; k < pend[j]; ++k)
            cols[basec + k] = (unsigned short)N;
    }
}

// ---- wave per (node, map); branchless 8-edge groups, cols prefetch ----
__global__ void csr_agg(const unsigned short* __restrict__ h, const int* __restrict__ rows,
                        const unsigned short* __restrict__ cols, int N, int NSB, int mapBase,
                        unsigned short* __restrict__ f) {
    const int g = blockIdx.y;
    const int m = mapBase + g;
    const int lane = threadIdx.x & 63;
    int n = (blockIdx.x * blockDim.x + threadIdx.x) >> 6;
    if (n >= N) return;
    const size_t base = (size_t)(m * NSB + (n >> SBSHIFT)) * CAPCOL;
    int s = ((n & 1023) == 0) ? (int)base : rows[(size_t)m * N + n - 1];
    int e = rows[(size_t)m * N + n];
    const unsigned short* hg = h + g * 64 + lane;

    float acc = 0.f;
    uint4 cur = *reinterpret_cast<const uint4*>(cols + s);  // wave-uniform 16B
    for (int i = s; i < e; i += 8) {
        uint4 nxt = *reinterpret_cast<const uint4*>(cols + i + 8);  // overread: slack
        unsigned c0 = cur.x & 0xffff, c1 = cur.x >> 16;
        unsigned c2 = cur.y & 0xffff, c3 = cur.y >> 16;
        unsigned c4 = cur.z & 0xffff, c5 = cur.z >> 16;
        unsigned c6 = cur.w & 0xffff, c7 = cur.w >> 16;
        float v0 = bf2f(hg[(size_t)c0 * 192]);
        float v1 = bf2f(hg[(size_t)c1 * 192]);
        float v2 = bf2f(hg[(size_t)c2 * 192]);
        float v3 = bf2f(hg[(size_t)c3 * 192]);
        float v4 = bf2f(hg[(size_t)c4 * 192]);
        float v5 = bf2f(hg[(size_t)c5 * 192]);
        float v6 = bf2f(hg[(size_t)c6 * 192]);
        float v7 = bf2f(hg[(size_t)c7 * 192]);
        acc += ((v0 + v1) + (v2 + v3)) + ((v4 + v5) + (v6 + v7));
        cur = nxt;
    }
    f[(size_t)n * 192 + g * 64 + lane] = f2bf(fmaxf(acc, 0.f));
}

// segment-pool bf16 f by sorted batch_idx; 32-row chunks for occupancy.
__global__ void pool_kernel(const unsigned short* __restrict__ f, const int* __restrict__ bidx,
                            int N, float* __restrict__ pooled) {
    const int c  = threadIdx.x;          // 0..191
    const int r0 = blockIdx.x * POOLROWS;
    const int r1 = min(r0 + POOLROWS, N);
    if (r0 >= N) return;
    float acc = 0.f;
    int cur = bidx[r0];
    for (int r = r0; r < r1; ++r) {
        int b = bidx[r];
        if (b != cur) {
            atomicAdd(&pooled[(size_t)cur * 192 + c], acc);
            acc = 0.f;
            cur = b;
        }
        acc += bf2f(f[(size_t)r * 192 + c]);
    }
    atomicAdd(&pooled[(size_t)cur * 192 + c], acc);
}

__global__ void mlp_kernel(const float* __restrict__ pooled,
                           const float* __restrict__ A1, const float* __restrict__ ba1,
                           const float* __restrict__ A2, const float* __restrict__ ba2,
                           float* __restrict__ out) {
    __shared__ float p[192];
    __shared__ float hid[256];
    const int b = blockIdx.x;
    const int t = threadIdx.x;
    if (t < 192) p[t] = pooled[(size_t)b * 192 + t];
    __syncthreads();
    float acc = ba1[t];
    for (int k = 0; k < 192; ++k) acc += p[k] * A1[(size_t)k * 256 + t];
    hid[t] = fmaxf(acc, 0.f);
    __syncthreads();
    if (t < 10) {
        float o = ba2[t];
        for (int k = 0; k < 256; ++k) o += hid[k] * A2[(size_t)k * 10 + t];
        out[(size_t)b * 10 + t] = o;
    }
}

extern "C" void kernel_launch(void* const* d_in, const int* in_sizes, int n_in,
                              void* d_out, int out_size, void* d_ws, size_t ws_size,
                              hipStream_t stream) {
    const float* x      = (const float*)d_in[0];
    const int*   map00  = (const int*)d_in[1];
    const int*   map01  = (const int*)d_in[2];
    const int*   map02  = (const int*)d_in[3];
    const int*   map10  = (const int*)d_in[4];
    const int*   map11  = (const int*)d_in[5];
    const int*   map12  = (const int*)d_in[6];
    const int*   bidx   = (const int*)d_in[7];
    const float* W00 = (const float*)d_in[9];  const float* b00 = (const float*)d_in[10];
    const float* W01 = (const float*)d_in[11]; const float* b01 = (const float*)d_in[12];
    const float* W02 = (const float*)d_in[13]; const float* b02 = (const float*)d_in[14];
    const float* W10 = (const float*)d_in[15]; const float* b10 = (const float*)d_in[16];
    const float* W11 = (const float*)d_in[17]; const float* b11 = (const float*)d_in[18];
    const float* W12 = (const float*)d_in[19]; const float* b12 = (const float*)d_in[20];
    const float* A1  = (const float*)d_in[21]; const float* ba1 = (const float*)d_in[22];
    const float* A2  = (const float*)d_in[23]; const float* ba2 = (const float*)d_in[24];

    const int N   = in_sizes[0] / 128;
    const int E   = in_sizes[1] / 2;
    const int NSB = (N + 1023) >> SBSHIFT;     // super-buckets of 1024 nodes

    unsigned short* bufH = (unsigned short*)d_ws;                    // [N+1,192] bf16
    unsigned short* bufF = bufH + (size_t)(N + 1) * 192;             // [N,192] bf16
    float*    pooled = (float*)(bufF + (size_t)N * 192);             // [64,192] f32
    int*      cnt    = (int*)(pooled + 64 * 192);                    // 6*NSB
    unsigned* p1     = (unsigned*)(cnt + 6 * NSB);                   // 6*NSB*CAPSB
    unsigned short* cols = (unsigned short*)(p1 + (size_t)6 * NSB * CAPSB); // +32 slack
    int*      rows   = (int*)(cols + (size_t)6 * NSB * CAPCOL + 32); // 6*N
    unsigned short* wpack = (unsigned short*)(rows + (size_t)6 * N); // 6*12288 bf16

    dim3 gemmGrid((N + 63) / 64, 3);
    dim3 p1Grid((E + CHUNK - 1) / CHUNK, 6);
    dim3 sortGrid(NSB, 6);
    dim3 aggGrid((N + 3) / 4, 3);

    // build CSR for all 6 maps + pack weights + zero dummy h row up front
    hipMemsetAsync(cnt, 0, (size_t)6 * NSB * sizeof(int), stream);
    prepack_w<<<7, 256, 0, stream>>>(W00, W01, W02, W10, W11, W12, wpack, bufH, N);
    part_coarse<<<p1Grid, PTHREADS, 0, stream>>>(map00, map01, map02,
                                                 map10, map11, map12,
                                                 E, NSB, cnt, p1);
    sb_sort<<<sortGrid, PTHREADS, 0, stream>>>(NSB, N, cnt, p1, cols, rows);
    // layer 0
    gemm_mfma<0><<<gemmGrid, 256, 0, stream>>>(x, N, 128, wpack, b00, b01, b02, 0, bufH);
    csr_agg<<<aggGrid, 256, 0, stream>>>(bufH, rows, cols, N, NSB, 0, bufF);
    // layer 1
    gemm_mfma<1><<<gemmGrid, 256, 0, stream>>>(bufF, N, 192, wpack, b10, b11, b12, 3, bufH);
    csr_agg<<<aggGrid, 256, 0, stream>>>(bufH, rows, cols, N, NSB, 3, bufF);
    // pool + mlp
    hipMemsetAsync(pooled, 0, 64 * 192 * sizeof(float), stream);
    pool_kernel<<<(N + POOLROWS - 1) / POOLROWS, 192, 0, stream>>>(bufF, bidx, N, pooled);
    mlp_kernel<<<64, 256, 0, stream>>>(pooled, A1, ba1, A2, ba2, (float*)d_out);
}

// Round 10
// 276.820 us; speedup vs baseline: 1.5071x; 1.0439x over previous
//
#include <hip/hip_runtime.h>
#include <hip/hip_bf16.h>

// ---------------------------------------------------------------------------
// DHN 2-layer hom-conv GNN.
// Round 10:
//  - csr_agg: 2 edges/wave-instr (half-wave per edge parity, ushort2 feature
//    pair per lane) -> VALU + gather-issue count halves; shfl_xor(32) merge.
//  - part_coarse: CHUNK 4096 (1176 blocks) + (dst,src) staged in registers ->
//    no dependent re-load in scatter loop, 33% less map traffic.
// ---------------------------------------------------------------------------

#define CAPSB 17408       // per-(map,SB) p1 capacity: mean 16384 + 8 sigma
#define CAPCOL 24576      // cols capacity: CAPSB + 1024*7 padding
#define CHUNK 4096        // edges per pass-1 block
#define PTHREADS 512
#define EPT 8             // CHUNK / PTHREADS
#define SBSHIFT 10        // 1024 nodes per super-bucket
#define POOLROWS 32       // rows per pool block

typedef __attribute__((ext_vector_type(8))) short bf16x8;
typedef __attribute__((ext_vector_type(4))) float f32x4;

__device__ inline unsigned short f2bf(float x) {           // RNE f32 -> bf16
    union { float f; unsigned u; } c; c.f = x;
    unsigned r = (c.u + 0x7FFFu + ((c.u >> 16) & 1u)) >> 16;
    return (unsigned short)r;
}
__device__ inline float bf2f(unsigned u16) {
    union { unsigned u; float f; } c; c.u = (u16 & 0xffffu) << 16; return c.f;
}

// ---- pack 6 weight matrices -> [K/8][64][8] bf16 frags; block 6 zeroes h[N] ----
__global__ void prepack_w(const float* __restrict__ W0, const float* __restrict__ W1,
                          const float* __restrict__ W2, const float* __restrict__ W3,
                          const float* __restrict__ W4, const float* __restrict__ W5,
                          unsigned short* __restrict__ wp,
                          unsigned short* __restrict__ h, int N) {
    const int m = blockIdx.x;
    if (m == 6) {                               // zero dummy row N of h
        for (int i = threadIdx.x; i < 192; i += 256) h[(size_t)N * 192 + i] = 0;
        return;
    }
    const float* W = (m == 0) ? W0 : (m == 1) ? W1 : (m == 2) ? W2
                   : (m == 3) ? W3 : (m == 4) ? W4 : W5;
    const int K = (m < 3) ? 128 : 192;
    unsigned short* o = wp + (size_t)m * 12288;
    for (int idx = threadIdx.x; idx < K * 64; idx += 256) {
        int k = idx >> 6, col = idx & 63;
        o[((k >> 3) * 64 + col) * 8 + (k & 7)] = f2bf(W[idx]);
    }
}

// ---- bf16 MFMA gemm: h[:, g*64..] = in[M,K]@Wg + bg, h bf16. ----
template <int INBF16>
__global__ void gemm_mfma(const void* __restrict__ in_, int M, int K,
                          const unsigned short* __restrict__ wpack,
                          const float* __restrict__ b0, const float* __restrict__ b1,
                          const float* __restrict__ b2, int mslot,
                          unsigned short* __restrict__ h) {
    __shared__ __align__(16) unsigned short Ws[12288];  // K*64 bf16, K<=192
    __shared__ __align__(16) unsigned short As[2048];   // 64 rows x 32 k, swizzled

    const int g = blockIdx.y;
    const float* bias = (g == 0) ? b0 : ((g == 1) ? b1 : b2);
    const unsigned short* wp = wpack + (size_t)(mslot + g) * 12288;

    const int t = threadIdx.x;
    for (int i = t; i < K * 32; i += 256)
        ((int*)Ws)[i] = ((const int*)wp)[i];

    const int m0   = blockIdx.x * 64;
    const int lane = t & 63;
    const int wrow = (t >> 6) * 16;

    const int arow = t >> 2;
    const int aseg = t & 3;
    const int aswz = arow * 32 + ((aseg ^ ((arow >> 1) & 3)) << 3);
    const int grow = m0 + arow;

    const float*          ainf = (const float*)in_ + (size_t)grow * K + aseg * 8;
    const unsigned short* ainb = (const unsigned short*)in_ + (size_t)grow * K + aseg * 8;

    const int lrow = wrow + (lane & 15);
    const int aoff = lrow * 32 + ((((lane >> 4)) ^ ((lrow >> 1) & 3)) << 3);
    const int kq   = lane >> 4;

    f32x4 acc[4] = {};

    const int nsteps = K >> 5;
    for (int s = 0; s < nsteps; ++s) {
        __syncthreads();
        bf16x8 av = {};
        if (grow < M) {
            if (INBF16) {
                av = *reinterpret_cast<const bf16x8*>(ainb + s * 32);
            } else {
                float4 v0 = *reinterpret_cast<const float4*>(ainf + s * 32);
                float4 v1 = *reinterpret_cast<const float4*>(ainf + s * 32 + 4);
                av[0] = (short)f2bf(v0.x); av[1] = (short)f2bf(v0.y);
                av[2] = (short)f2bf(v0.z); av[3] = (short)f2bf(v0.w);
                av[4] = (short)f2bf(v1.x); av[5] = (short)f2bf(v1.y);
                av[6] = (short)f2bf(v1.z); av[7] = (short)f2bf(v1.w);
            }
        }
        *reinterpret_cast<bf16x8*>(&As[aswz]) = av;
        __syncthreads();

        bf16x8 af = *reinterpret_cast<const bf16x8*>(&As[aoff]);
        const int kg = s * 4 + kq;
        #pragma unroll
        for (int n = 0; n < 4; ++n) {
            bf16x8 bfv = *reinterpret_cast<const bf16x8*>(
                &Ws[(size_t)(kg * 64 + n * 16 + (lane & 15)) * 8]);
            acc[n] = __builtin_amdgcn_mfma_f32_16x16x32_bf16(af, bfv, acc[n], 0, 0, 0);
        }
    }

    #pragma unroll
    for (int n = 0; n < 4; ++n) {
        int col = n * 16 + (lane & 15);
        float bv = bias[col];
        #pragma unroll
        for (int r = 0; r < 4; ++r) {
            int row = m0 + wrow + (lane >> 4) * 4 + r;
            if (row < M)
                h[(size_t)row * 192 + g * 64 + col] = f2bf(acc[n][r] + bv);
        }
    }
}

// ---- pass 1: coarse partition into 1024-node super-buckets ----
// grid (ceil(E/CHUNK), 6), block 512, 8 edges/thread staged in registers.
__global__ void part_coarse(const int* __restrict__ m0, const int* __restrict__ m1,
                            const int* __restrict__ m2, const int* __restrict__ m3,
                            const int* __restrict__ m4, const int* __restrict__ m5,
                            int E, int NSB, int* __restrict__ cnt,
                            unsigned* __restrict__ p1) {
    const int m = blockIdx.y;
    const int* mp = (m == 0) ? m0 : (m == 1) ? m1 : (m == 2) ? m2
                  : (m == 3) ? m3 : (m == 4) ? m4 : m5;
    __shared__ int hist[64];
    __shared__ int base[64];
    const int c0 = blockIdx.x * CHUNK;
    const int t = threadIdx.x;

    int d[EPT]; unsigned srcs[EPT];
    #pragma unroll
    for (int k = 0; k < EPT; ++k) {
        int e = c0 + k * PTHREADS + t;
        bool v = e < E;
        d[k]    = v ? mp[e] : -1;
        srcs[k] = v ? (unsigned)mp[E + e] : 0u;
    }

    if (t < 64) hist[t] = 0;
    __syncthreads();
    #pragma unroll
    for (int k = 0; k < EPT; ++k)
        if (d[k] >= 0) atomicAdd(&hist[d[k] >> SBSHIFT], 1);
    __syncthreads();
    if (t < NSB) {
        int c = hist[t];
        base[t] = (c > 0) ? atomicAdd(&cnt[m * NSB + t], c) : 0;
    }
    __syncthreads();
    if (t < NSB) hist[t] = base[t];
    __syncthreads();
    #pragma unroll
    for (int k = 0; k < EPT; ++k) {
        if (d[k] >= 0) {
            int sb = d[k] >> SBSHIFT;
            int pos = atomicAdd(&hist[sb], 1);
            if (pos < CAPSB)
                p1[(size_t)(m * NSB + sb) * CAPSB + pos] = (srcs[k] << 16) | (unsigned)d[k];
        }
    }
}

// ---- pass 2: per-(SB,map) counting sort -> padded CSR (u16 cols). ----
__global__ void sb_sort(int NSB, int N, const int* __restrict__ cnt,
                        const unsigned* __restrict__ p1,
                        unsigned short* __restrict__ cols, int* __restrict__ rows) {
    const int sb = blockIdx.x;
    const int m  = blockIdx.y;
    __shared__ int bin[1024];
    __shared__ int pend[1024];
    __shared__ int scanbuf[512];
    const int t = threadIdx.x;
    const size_t basep = (size_t)(m * NSB + sb) * CAPSB;
    const size_t basec = (size_t)(m * NSB + sb) * CAPCOL;
    const int c = min(cnt[m * NSB + sb], CAPSB);

    bin[t] = 0; bin[t + 512] = 0;
    __syncthreads();
    for (int i = t; i < c; i += 512)
        atomicAdd(&bin[p1[basep + i] & 1023], 1);
    __syncthreads();

    int b0 = bin[2 * t], b1 = bin[2 * t + 1];
    int p0 = (b0 + 7) & ~7, p1v = (b1 + 7) & ~7;
    int tsum = p0 + p1v;
    scanbuf[t] = tsum;
    __syncthreads();
    for (int off = 1; off < 512; off <<= 1) {
        int v = (t >= off) ? scanbuf[t - off] : 0;
        __syncthreads();
        scanbuf[t] += v;
        __syncthreads();
    }
    int excl = scanbuf[t] - tsum;
    bin[2 * t]      = excl;
    pend[2 * t]     = excl + p0;
    bin[2 * t + 1]  = excl + p0;
    pend[2 * t + 1] = excl + p0 + p1v;
    __syncthreads();

    for (int j = t; j < 1024; j += 512) {
        int n = (sb << SBSHIFT) + j;
        if (n < N) rows[(size_t)m * N + n] = (int)(basec + pend[j]);
    }
    __syncthreads();

    for (int i = t; i < c; i += 512) {
        unsigned r = p1[basep + i];
        int pos = atomicAdd(&bin[r & 1023], 1);
        cols[basec + pos] = (unsigned short)(r >> 16);
    }
    __syncthreads();

    for (int j = t; j < 1024; j += 512) {
        for (int k = bin[j]; k < pend[j]; ++k)
            cols[basec + k] = (unsigned short)N;
    }
}

// ---- wave per (node, map); 2 edges per instruction (half-wave parity), ----
// ---- ushort2 feature pair per lane, shfl_xor(32) merge at the end.     ----
__global__ void csr_agg(const unsigned short* __restrict__ h, const int* __restrict__ rows,
                        const unsigned short* __restrict__ cols, int N, int NSB, int mapBase,
                        unsigned short* __restrict__ f) {
    const int g = blockIdx.y;
    const int m = mapBase + g;
    const int lane = threadIdx.x & 63;
    const int hi = lane >> 5;            // 0: even edges, 1: odd edges
    const int fp = (lane & 31) * 2;      // feature pair base
    int n = (blockIdx.x * blockDim.x + threadIdx.x) >> 6;
    if (n >= N) return;
    const size_t base = (size_t)(m * NSB + (n >> SBSHIFT)) * CAPCOL;
    int s = ((n & 1023) == 0) ? (int)base : rows[(size_t)m * N + n - 1];
    int e = rows[(size_t)m * N + n];
    const unsigned short* hg = h + g * 64 + fp;

    float ax = 0.f, ay = 0.f;
    uint4 cur = *reinterpret_cast<const uint4*>(cols + s);  // wave-uniform 16B
    for (int i = s; i < e; i += 8) {
        uint4 nxt = *reinterpret_cast<const uint4*>(cols + i + 8);  // overread: slack
        unsigned e0 = hi ? (cur.x >> 16) : (cur.x & 0xffff);
        unsigned e1 = hi ? (cur.y >> 16) : (cur.y & 0xffff);
        unsigned e2 = hi ? (cur.z >> 16) : (cur.z & 0xffff);
        unsigned e3 = hi ? (cur.w >> 16) : (cur.w & 0xffff);
        unsigned v0 = *reinterpret_cast<const unsigned*>(hg + (size_t)e0 * 192);
        unsigned v1 = *reinterpret_cast<const unsigned*>(hg + (size_t)e1 * 192);
        unsigned v2 = *reinterpret_cast<const unsigned*>(hg + (size_t)e2 * 192);
        unsigned v3 = *reinterpret_cast<const unsigned*>(hg + (size_t)e3 * 192);
        ax += (bf2f(v0) + bf2f(v1)) + (bf2f(v2) + bf2f(v3));
        ay += (bf2f(v0 >> 16) + bf2f(v1 >> 16)) + (bf2f(v2 >> 16) + bf2f(v3 >> 16));
        cur = nxt;
    }
    ax += __shfl_xor(ax, 32);
    ay += __shfl_xor(ay, 32);
    if (hi == 0) {
        unsigned pk = (unsigned)f2bf(fmaxf(ax, 0.f)) | ((unsigned)f2bf(fmaxf(ay, 0.f)) << 16);
        *reinterpret_cast<unsigned*>(f + (size_t)n * 192 + g * 64 + fp) = pk;
    }
}

// segment-pool bf16 f by sorted batch_idx; 32-row chunks for occupancy.
__global__ void pool_kernel(const unsigned short* __restrict__ f, const int* __restrict__ bidx,
                            int N, float* __restrict__ pooled) {
    const int c  = threadIdx.x;          // 0..191
    const int r0 = blockIdx.x * POOLROWS;
    const int r1 = min(r0 + POOLROWS, N);
    if (r0 >= N) return;
    float acc = 0.f;
    int cur = bidx[r0];
    for (int r = r0; r < r1; ++r) {
        int b = bidx[r];
        if (b != cur) {
            atomicAdd(&pooled[(size_t)cur * 192 + c], acc);
            acc = 0.f;
            cur = b;
        }
        acc += bf2f(f[(size_t)r * 192 + c]);
    }
    atomicAdd(&pooled[(size_t)cur * 192 + c], acc);
}

__global__ void mlp_kernel(const float* __restrict__ pooled,
                           const float* __restrict__ A1, const float* __restrict__ ba1,
                           const float* __restrict__ A2, const float* __restrict__ ba2,
                           float* __restrict__ out) {
    __shared__ float p[192];
    __shared__ float hid[256];
    const int b = blockIdx.x;
    const int t = threadIdx.x;
    if (t < 192) p[t] = pooled[(size_t)b * 192 + t];
    __syncthreads();
    float acc = ba1[t];
    for (int k = 0; k < 192; ++k) acc += p[k] * A1[(size_t)k * 256 + t];
    hid[t] = fmaxf(acc, 0.f);
    __syncthreads();
    if (t < 10) {
        float o = ba2[t];
        for (int k = 0; k < 256; ++k) o += hid[k] * A2[(size_t)k * 10 + t];
        out[(size_t)b * 10 + t] = o;
    }
}

extern "C" void kernel_launch(void* const* d_in, const int* in_sizes, int n_in,
                              void* d_out, int out_size, void* d_ws, size_t ws_size,
                              hipStream_t stream) {
    const float* x      = (const float*)d_in[0];
    const int*   map00  = (const int*)d_in[1];
    const int*   map01  = (const int*)d_in[2];
    const int*   map02  = (const int*)d_in[3];
    const int*   map10  = (const int*)d_in[4];
    const int*   map11  = (const int*)d_in[5];
    const int*   map12  = (const int*)d_in[6];
    const int*   bidx   = (const int*)d_in[7];
    const float* W00 = (const float*)d_in[9];  const float* b00 = (const float*)d_in[10];
    const float* W01 = (const float*)d_in[11]; const float* b01 = (const float*)d_in[12];
    const float* W02 = (const float*)d_in[13]; const float* b02 = (const float*)d_in[14];
    const float* W10 = (const float*)d_in[15]; const float* b10 = (const float*)d_in[16];
    const float* W11 = (const float*)d_in[17]; const float* b11 = (const float*)d_in[18];
    const float* W12 = (const float*)d_in[19]; const float* b12 = (const float*)d_in[20];
    const float* A1  = (const float*)d_in[21]; const float* ba1 = (const float*)d_in[22];
    const float* A2  = (const float*)d_in[23]; const float* ba2 = (const float*)d_in[24];

    const int N   = in_sizes[0] / 128;
    const int E   = in_sizes[1] / 2;
    const int NSB = (N + 1023) >> SBSHIFT;     // super-buckets of 1024 nodes

    unsigned short* bufH = (unsigned short*)d_ws;                    // [N+1,192] bf16
    unsigned short* bufF = bufH + (size_t)(N + 1) * 192;             // [N,192] bf16
    float*    pooled = (float*)(bufF + (size_t)N * 192);             // [64,192] f32
    int*      cnt    = (int*)(pooled + 64 * 192);                    // 6*NSB
    unsigned* p1     = (unsigned*)(cnt + 6 * NSB);                   // 6*NSB*CAPSB
    unsigned short* cols = (unsigned short*)(p1 + (size_t)6 * NSB * CAPSB); // +32 slack
    int*      rows   = (int*)(cols + (size_t)6 * NSB * CAPCOL + 32); // 6*N
    unsigned short* wpack = (unsigned short*)(rows + (size_t)6 * N); // 6*12288 bf16

    dim3 gemmGrid((N + 63) / 64, 3);
    dim3 p1Grid((E + CHUNK - 1) / CHUNK, 6);
    dim3 sortGrid(NSB, 6);
    dim3 aggGrid((N + 3) / 4, 3);

    // build CSR for all 6 maps + pack weights + zero dummy h row up front
    hipMemsetAsync(cnt, 0, (size_t)6 * NSB * sizeof(int), stream);
    prepack_w<<<7, 256, 0, stream>>>(W00, W01, W02, W10, W11, W12, wpack, bufH, N);
    part_coarse<<<p1Grid, PTHREADS, 0, stream>>>(map00, map01, map02,
                                                 map10, map11, map12,
                                                 E, NSB, cnt, p1);
    sb_sort<<<sortGrid, PTHREADS, 0, stream>>>(NSB, N, cnt, p1, cols, rows);
    // layer 0
    gemm_mfma<0><<<gemmGrid, 256, 0, stream>>>(x, N, 128, wpack, b00, b01, b02, 0, bufH);
    csr_agg<<<aggGrid, 256, 0, stream>>>(bufH, rows, cols, N, NSB, 0, bufF);
    // layer 1
    gemm_mfma<1><<<gemmGrid, 256, 0, stream>>>(bufF, N, 192, wpack, b10, b11, b12, 3, bufH);
    csr_agg<<<aggGrid, 256, 0, stream>>>(bufH, rows, cols, N, NSB, 3, bufF);
    // pool + mlp
    hipMemsetAsync(pooled, 0, 64 * 192 * sizeof(float), stream);
    pool_kernel<<<(N + POOLROWS - 1) / POOLROWS, 192, 0, stream>>>(bufF, bidx, N, pooled);
    mlp_kernel<<<64, 256, 0, stream>>>(pooled, A1, ba1, A2, ba2, (float*)d_out);
}

// Round 11
// 256.793 us; speedup vs baseline: 1.6247x; 1.0780x over previous
//
#include <hip/hip_runtime.h>
#include <hip/hip_bf16.h>

// ---------------------------------------------------------------------------
// DHN 2-layer hom-conv GNN.
// Round 11: csr_agg is latency/MLP-bound (r10: halved VALU -> no change;
// 5.2TB/s effective, 30% L2 miss to L3 ~500cyc, only 8 gathers in flight).
// Unroll to 16 edges/iter: 16 independent gathers issued up front, 8-edge
// tail for the x8-padded runs. MLP per wave doubles.
// ---------------------------------------------------------------------------

#define CAPSB 17408       // per-(map,SB) p1 capacity: mean 16384 + 8 sigma
#define CAPCOL 24576      // cols capacity: CAPSB + 1024*7 padding
#define CHUNK 4096        // edges per pass-1 block
#define PTHREADS 512
#define EPT 8             // CHUNK / PTHREADS
#define SBSHIFT 10        // 1024 nodes per super-bucket
#define POOLROWS 32       // rows per pool block

typedef __attribute__((ext_vector_type(8))) short bf16x8;
typedef __attribute__((ext_vector_type(4))) float f32x4;

__device__ inline unsigned short f2bf(float x) {           // RNE f32 -> bf16
    union { float f; unsigned u; } c; c.f = x;
    unsigned r = (c.u + 0x7FFFu + ((c.u >> 16) & 1u)) >> 16;
    return (unsigned short)r;
}
__device__ inline float bf2f(unsigned u16) {
    union { unsigned u; float f; } c; c.u = (u16 & 0xffffu) << 16; return c.f;
}

// ---- pack 6 weight matrices -> [K/8][64][8] bf16 frags; block 6 zeroes h[N] ----
__global__ void prepack_w(const float* __restrict__ W0, const float* __restrict__ W1,
                          const float* __restrict__ W2, const float* __restrict__ W3,
                          const float* __restrict__ W4, const float* __restrict__ W5,
                          unsigned short* __restrict__ wp,
                          unsigned short* __restrict__ h, int N) {
    const int m = blockIdx.x;
    if (m == 6) {                               // zero dummy row N of h
        for (int i = threadIdx.x; i < 192; i += 256) h[(size_t)N * 192 + i] = 0;
        return;
    }
    const float* W = (m == 0) ? W0 : (m == 1) ? W1 : (m == 2) ? W2
                   : (m == 3) ? W3 : (m == 4) ? W4 : W5;
    const int K = (m < 3) ? 128 : 192;
    unsigned short* o = wp + (size_t)m * 12288;
    for (int idx = threadIdx.x; idx < K * 64; idx += 256) {
        int k = idx >> 6, col = idx & 63;
        o[((k >> 3) * 64 + col) * 8 + (k & 7)] = f2bf(W[idx]);
    }
}

// ---- bf16 MFMA gemm: h[:, g*64..] = in[M,K]@Wg + bg, h bf16. ----
template <int INBF16>
__global__ void gemm_mfma(const void* __restrict__ in_, int M, int K,
                          const unsigned short* __restrict__ wpack,
                          const float* __restrict__ b0, const float* __restrict__ b1,
                          const float* __restrict__ b2, int mslot,
                          unsigned short* __restrict__ h) {
    __shared__ __align__(16) unsigned short Ws[12288];  // K*64 bf16, K<=192
    __shared__ __align__(16) unsigned short As[2048];   // 64 rows x 32 k, swizzled

    const int g = blockIdx.y;
    const float* bias = (g == 0) ? b0 : ((g == 1) ? b1 : b2);
    const unsigned short* wp = wpack + (size_t)(mslot + g) * 12288;

    const int t = threadIdx.x;
    for (int i = t; i < K * 32; i += 256)
        ((int*)Ws)[i] = ((const int*)wp)[i];

    const int m0   = blockIdx.x * 64;
    const int lane = t & 63;
    const int wrow = (t >> 6) * 16;

    const int arow = t >> 2;
    const int aseg = t & 3;
    const int aswz = arow * 32 + ((aseg ^ ((arow >> 1) & 3)) << 3);
    const int grow = m0 + arow;

    const float*          ainf = (const float*)in_ + (size_t)grow * K + aseg * 8;
    const unsigned short* ainb = (const unsigned short*)in_ + (size_t)grow * K + aseg * 8;

    const int lrow = wrow + (lane & 15);
    const int aoff = lrow * 32 + ((((lane >> 4)) ^ ((lrow >> 1) & 3)) << 3);
    const int kq   = lane >> 4;

    f32x4 acc[4] = {};

    const int nsteps = K >> 5;
    for (int s = 0; s < nsteps; ++s) {
        __syncthreads();
        bf16x8 av = {};
        if (grow < M) {
            if (INBF16) {
                av = *reinterpret_cast<const bf16x8*>(ainb + s * 32);
            } else {
                float4 v0 = *reinterpret_cast<const float4*>(ainf + s * 32);
                float4 v1 = *reinterpret_cast<const float4*>(ainf + s * 32 + 4);
                av[0] = (short)f2bf(v0.x); av[1] = (short)f2bf(v0.y);
                av[2] = (short)f2bf(v0.z); av[3] = (short)f2bf(v0.w);
                av[4] = (short)f2bf(v1.x); av[5] = (short)f2bf(v1.y);
                av[6] = (short)f2bf(v1.z); av[7] = (short)f2bf(v1.w);
            }
        }
        *reinterpret_cast<bf16x8*>(&As[aswz]) = av;
        __syncthreads();

        bf16x8 af = *reinterpret_cast<const bf16x8*>(&As[aoff]);
        const int kg = s * 4 + kq;
        #pragma unroll
        for (int n = 0; n < 4; ++n) {
            bf16x8 bfv = *reinterpret_cast<const bf16x8*>(
                &Ws[(size_t)(kg * 64 + n * 16 + (lane & 15)) * 8]);
            acc[n] = __builtin_amdgcn_mfma_f32_16x16x32_bf16(af, bfv, acc[n], 0, 0, 0);
        }
    }

    #pragma unroll
    for (int n = 0; n < 4; ++n) {
        int col = n * 16 + (lane & 15);
        float bv = bias[col];
        #pragma unroll
        for (int r = 0; r < 4; ++r) {
            int row = m0 + wrow + (lane >> 4) * 4 + r;
            if (row < M)
                h[(size_t)row * 192 + g * 64 + col] = f2bf(acc[n][r] + bv);
        }
    }
}

// ---- pass 1: coarse partition into 1024-node super-buckets ----
__global__ void part_coarse(const int* __restrict__ m0, const int* __restrict__ m1,
                            const int* __restrict__ m2, const int* __restrict__ m3,
                            const int* __restrict__ m4, const int* __restrict__ m5,
                            int E, int NSB, int* __restrict__ cnt,
                            unsigned* __restrict__ p1) {
    const int m = blockIdx.y;
    const int* mp = (m == 0) ? m0 : (m == 1) ? m1 : (m == 2) ? m2
                  : (m == 3) ? m3 : (m == 4) ? m4 : m5;
    __shared__ int hist[64];
    __shared__ int base[64];
    const int c0 = blockIdx.x * CHUNK;
    const int t = threadIdx.x;

    int d[EPT]; unsigned srcs[EPT];
    #pragma unroll
    for (int k = 0; k < EPT; ++k) {
        int e = c0 + k * PTHREADS + t;
        bool v = e < E;
        d[k]    = v ? mp[e] : -1;
        srcs[k] = v ? (unsigned)mp[E + e] : 0u;
    }

    if (t < 64) hist[t] = 0;
    __syncthreads();
    #pragma unroll
    for (int k = 0; k < EPT; ++k)
        if (d[k] >= 0) atomicAdd(&hist[d[k] >> SBSHIFT], 1);
    __syncthreads();
    if (t < NSB) {
        int c = hist[t];
        base[t] = (c > 0) ? atomicAdd(&cnt[m * NSB + t], c) : 0;
    }
    __syncthreads();
    if (t < NSB) hist[t] = base[t];
    __syncthreads();
    #pragma unroll
    for (int k = 0; k < EPT; ++k) {
        if (d[k] >= 0) {
            int sb = d[k] >> SBSHIFT;
            int pos = atomicAdd(&hist[sb], 1);
            if (pos < CAPSB)
                p1[(size_t)(m * NSB + sb) * CAPSB + pos] = (srcs[k] << 16) | (unsigned)d[k];
        }
    }
}

// ---- pass 2: per-(SB,map) counting sort -> padded CSR (u16 cols). ----
__global__ void sb_sort(int NSB, int N, const int* __restrict__ cnt,
                        const unsigned* __restrict__ p1,
                        unsigned short* __restrict__ cols, int* __restrict__ rows) {
    const int sb = blockIdx.x;
    const int m  = blockIdx.y;
    __shared__ int bin[1024];
    __shared__ int pend[1024];
    __shared__ int scanbuf[512];
    const int t = threadIdx.x;
    const size_t basep = (size_t)(m * NSB + sb) * CAPSB;
    const size_t basec = (size_t)(m * NSB + sb) * CAPCOL;
    const int c = min(cnt[m * NSB + sb], CAPSB);

    bin[t] = 0; bin[t + 512] = 0;
    __syncthreads();
    for (int i = t; i < c; i += 512)
        atomicAdd(&bin[p1[basep + i] & 1023], 1);
    __syncthreads();

    int b0 = bin[2 * t], b1 = bin[2 * t + 1];
    int p0 = (b0 + 7) & ~7, p1v = (b1 + 7) & ~7;
    int tsum = p0 + p1v;
    scanbuf[t] = tsum;
    __syncthreads();
    for (int off = 1; off < 512; off <<= 1) {
        int v = (t >= off) ? scanbuf[t - off] : 0;
        __syncthreads();
        scanbuf[t] += v;
        __syncthreads();
    }
    int excl = scanbuf[t] - tsum;
    bin[2 * t]      = excl;
    pend[2 * t]     = excl + p0;
    bin[2 * t + 1]  = excl + p0;
    pend[2 * t + 1] = excl + p0 + p1v;
    __syncthreads();

    for (int j = t; j < 1024; j += 512) {
        int n = (sb << SBSHIFT) + j;
        if (n < N) rows[(size_t)m * N + n] = (int)(basec + pend[j]);
    }
    __syncthreads();

    for (int i = t; i < c; i += 512) {
        unsigned r = p1[basep + i];
        int pos = atomicAdd(&bin[r & 1023], 1);
        cols[basec + pos] = (unsigned short)(r >> 16);
    }
    __syncthreads();

    for (int j = t; j < 1024; j += 512) {
        for (int k = bin[j]; k < pend[j]; ++k)
            cols[basec + k] = (unsigned short)N;
    }
}

// ---- wave per (node, map); 16 edges/iter (2 uint4 groups, 16 gathers in
// ---- flight), 8-edge tail; half-wave parity, ushort2/lane, shfl merge. ----
__global__ void csr_agg(const unsigned short* __restrict__ h, const int* __restrict__ rows,
                        const unsigned short* __restrict__ cols, int N, int NSB, int mapBase,
                        unsigned short* __restrict__ f) {
    const int g = blockIdx.y;
    const int m = mapBase + g;
    const int lane = threadIdx.x & 63;
    const int hsh = (lane >> 5) * 16;    // 0: even edges, 16: odd edges
    const int fp = (lane & 31) * 2;      // feature pair base
    int n = (blockIdx.x * blockDim.x + threadIdx.x) >> 6;
    if (n >= N) return;
    const size_t base = (size_t)(m * NSB + (n >> SBSHIFT)) * CAPCOL;
    int s = ((n & 1023) == 0) ? (int)base : rows[(size_t)m * N + n - 1];
    int e = rows[(size_t)m * N + n];
    const unsigned short* hg = h + g * 64 + fp;

    float ax = 0.f, ay = 0.f;
    int i = s;
    for (; i + 16 <= e; i += 16) {
        uint4 ca = *reinterpret_cast<const uint4*>(cols + i);
        uint4 cb = *reinterpret_cast<const uint4*>(cols + i + 8);
        unsigned a0 = (ca.x >> hsh) & 0xffff, a1 = (ca.y >> hsh) & 0xffff;
        unsigned a2 = (ca.z >> hsh) & 0xffff, a3 = (ca.w >> hsh) & 0xffff;
        unsigned b0 = (cb.x >> hsh) & 0xffff, b1 = (cb.y >> hsh) & 0xffff;
        unsigned b2 = (cb.z >> hsh) & 0xffff, b3 = (cb.w >> hsh) & 0xffff;
        unsigned va0 = *reinterpret_cast<const unsigned*>(hg + (size_t)a0 * 192);
        unsigned va1 = *reinterpret_cast<const unsigned*>(hg + (size_t)a1 * 192);
        unsigned va2 = *reinterpret_cast<const unsigned*>(hg + (size_t)a2 * 192);
        unsigned va3 = *reinterpret_cast<const unsigned*>(hg + (size_t)a3 * 192);
        unsigned vb0 = *reinterpret_cast<const unsigned*>(hg + (size_t)b0 * 192);
        unsigned vb1 = *reinterpret_cast<const unsigned*>(hg + (size_t)b1 * 192);
        unsigned vb2 = *reinterpret_cast<const unsigned*>(hg + (size_t)b2 * 192);
        unsigned vb3 = *reinterpret_cast<const unsigned*>(hg + (size_t)b3 * 192);
        ax += ((bf2f(va0) + bf2f(va1)) + (bf2f(va2) + bf2f(va3)))
            + ((bf2f(vb0) + bf2f(vb1)) + (bf2f(vb2) + bf2f(vb3)));
        ay += ((bf2f(va0 >> 16) + bf2f(va1 >> 16)) + (bf2f(va2 >> 16) + bf2f(va3 >> 16)))
            + ((bf2f(vb0 >> 16) + bf2f(vb1 >> 16)) + (bf2f(vb2 >> 16) + bf2f(vb3 >> 16)));
    }
    if (i < e) {   // exactly 8 remaining (runs are x8-padded)
        uint4 ca = *reinterpret_cast<const uint4*>(cols + i);
        unsigned a0 = (ca.x >> hsh) & 0xffff, a1 = (ca.y >> hsh) & 0xffff;
        unsigned a2 = (ca.z >> hsh) & 0xffff, a3 = (ca.w >> hsh) & 0xffff;
        unsigned va0 = *reinterpret_cast<const unsigned*>(hg + (size_t)a0 * 192);
        unsigned va1 = *reinterpret_cast<const unsigned*>(hg + (size_t)a1 * 192);
        unsigned va2 = *reinterpret_cast<const unsigned*>(hg + (size_t)a2 * 192);
        unsigned va3 = *reinterpret_cast<const unsigned*>(hg + (size_t)a3 * 192);
        ax += (bf2f(va0) + bf2f(va1)) + (bf2f(va2) + bf2f(va3));
        ay += (bf2f(va0 >> 16) + bf2f(va1 >> 16)) + (bf2f(va2 >> 16) + bf2f(va3 >> 16));
    }
    ax += __shfl_xor(ax, 32);
    ay += __shfl_xor(ay, 32);
    if (hsh == 0) {
        unsigned pk = (unsigned)f2bf(fmaxf(ax, 0.f)) | ((unsigned)f2bf(fmaxf(ay, 0.f)) << 16);
        *reinterpret_cast<unsigned*>(f + (size_t)n * 192 + g * 64 + fp) = pk;
    }
}

// segment-pool bf16 f by sorted batch_idx; 32-row chunks for occupancy.
__global__ void pool_kernel(const unsigned short* __restrict__ f, const int* __restrict__ bidx,
                            int N, float* __restrict__ pooled) {
    const int c  = threadIdx.x;          // 0..191
    const int r0 = blockIdx.x * POOLROWS;
    const int r1 = min(r0 + POOLROWS, N);
    if (r0 >= N) return;
    float acc = 0.f;
    int cur = bidx[r0];
    for (int r = r0; r < r1; ++r) {
        int b = bidx[r];
        if (b != cur) {
            atomicAdd(&pooled[(size_t)cur * 192 + c], acc);
            acc = 0.f;
            cur = b;
        }
        acc += bf2f(f[(size_t)r * 192 + c]);
    }
    atomicAdd(&pooled[(size_t)cur * 192 + c], acc);
}

__global__ void mlp_kernel(const float* __restrict__ pooled,
                           const float* __restrict__ A1, const float* __restrict__ ba1,
                           const float* __restrict__ A2, const float* __restrict__ ba2,
                           float* __restrict__ out) {
    __shared__ float p[192];
    __shared__ float hid[256];
    const int b = blockIdx.x;
    const int t = threadIdx.x;
    if (t < 192) p[t] = pooled[(size_t)b * 192 + t];
    __syncthreads();
    float acc = ba1[t];
    for (int k = 0; k < 192; ++k) acc += p[k] * A1[(size_t)k * 256 + t];
    hid[t] = fmaxf(acc, 0.f);
    __syncthreads();
    if (t < 10) {
        float o = ba2[t];
        for (int k = 0; k < 256; ++k) o += hid[k] * A2[(size_t)k * 10 + t];
        out[(size_t)b * 10 + t] = o;
    }
}

extern "C" void kernel_launch(void* const* d_in, const int* in_sizes, int n_in,
                              void* d_out, int out_size, void* d_ws, size_t ws_size,
                              hipStream_t stream) {
    const float* x      = (const float*)d_in[0];
    const int*   map00  = (const int*)d_in[1];
    const int*   map01  = (const int*)d_in[2];
    const int*   map02  = (const int*)d_in[3];
    const int*   map10  = (const int*)d_in[4];
    const int*   map11  = (const int*)d_in[5];
    const int*   map12  = (const int*)d_in[6];
    const int*   bidx   = (const int*)d_in[7];
    const float* W00 = (const float*)d_in[9];  const float* b00 = (const float*)d_in[10];
    const float* W01 = (const float*)d_in[11]; const float* b01 = (const float*)d_in[12];
    const float* W02 = (const float*)d_in[13]; const float* b02 = (const float*)d_in[14];
    const float* W10 = (const float*)d_in[15]; const float* b10 = (const float*)d_in[16];
    const float* W11 = (const float*)d_in[17]; const float* b11 = (const float*)d_in[18];
    const float* W12 = (const float*)d_in[19]; const float* b12 = (const float*)d_in[20];
    const float* A1  = (const float*)d_in[21]; const float* ba1 = (const float*)d_in[22];
    const float* A2  = (const float*)d_in[23]; const float* ba2 = (const float*)d_in[24];

    const int N   = in_sizes[0] / 128;
    const int E   = in_sizes[1] / 2;
    const int NSB = (N + 1023) >> SBSHIFT;     // super-buckets of 1024 nodes

    unsigned short* bufH = (unsigned short*)d_ws;                    // [N+1,192] bf16
    unsigned short* bufF = bufH + (size_t)(N + 1) * 192;             // [N,192] bf16
    float*    pooled = (float*)(bufF + (size_t)N * 192);             // [64,192] f32
    int*      cnt    = (int*)(pooled + 64 * 192);                    // 6*NSB
    unsigned* p1     = (unsigned*)(cnt + 6 * NSB);                   // 6*NSB*CAPSB
    unsigned short* cols = (unsigned short*)(p1 + (size_t)6 * NSB * CAPSB); // +32 slack
    int*      rows   = (int*)(cols + (size_t)6 * NSB * CAPCOL + 32); // 6*N
    unsigned short* wpack = (unsigned short*)(rows + (size_t)6 * N); // 6*12288 bf16

    dim3 gemmGrid((N + 63) / 64, 3);
    dim3 p1Grid((E + CHUNK - 1) / CHUNK, 6);
    dim3 sortGrid(NSB, 6);
    dim3 aggGrid((N + 3) / 4, 3);

    // build CSR for all 6 maps + pack weights + zero dummy h row up front
    hipMemsetAsync(cnt, 0, (size_t)6 * NSB * sizeof(int), stream);
    prepack_w<<<7, 256, 0, stream>>>(W00, W01, W02, W10, W11, W12, wpack, bufH, N);
    part_coarse<<<p1Grid, PTHREADS, 0, stream>>>(map00, map01, map02,
                                                 map10, map11, map12,
                                                 E, NSB, cnt, p1);
    sb_sort<<<sortGrid, PTHREADS, 0, stream>>>(NSB, N, cnt, p1, cols, rows);
    // layer 0
    gemm_mfma<0><<<gemmGrid, 256, 0, stream>>>(x, N, 128, wpack, b00, b01, b02, 0, bufH);
    csr_agg<<<aggGrid, 256, 0, stream>>>(bufH, rows, cols, N, NSB, 0, bufF);
    // layer 1
    gemm_mfma<1><<<gemmGrid, 256, 0, stream>>>(bufF, N, 192, wpack, b10, b11, b12, 3, bufH);
    csr_agg<<<aggGrid, 256, 0, stream>>>(bufH, rows, cols, N, NSB, 3, bufF);
    // pool + mlp
    hipMemsetAsync(pooled, 0, 64 * 192 * sizeof(float), stream);
    pool_kernel<<<(N + POOLROWS - 1) / POOLROWS, 192, 0, stream>>>(bufF, bidx, N, pooled);
    mlp_kernel<<<64, 256, 0, stream>>>(pooled, A1, ba1, A2, ba2, (float*)d_out);
}

// Round 12
// 238.793 us; speedup vs baseline: 1.7471x; 1.0754x over previous
//
#include <hip/hip_runtime.h>
#include <hip/hip_bf16.h>

// ---------------------------------------------------------------------------
// DHN 2-layer hom-conv GNN.
// Round 12: csr_agg MLP still capped by run length (~16 edges -> 8 loads in
// flight, one stall window per wave). Two nodes per wave: typical case issues
// 16 dword gathers before any accumulate (2x in-flight), halves wave count.
// ---------------------------------------------------------------------------

#define CAPSB 17408       // per-(map,SB) p1 capacity: mean 16384 + 8 sigma
#define CAPCOL 24576      // cols capacity: CAPSB + 1024*7 padding
#define CHUNK 4096        // edges per pass-1 block
#define PTHREADS 512
#define EPT 8             // CHUNK / PTHREADS
#define SBSHIFT 10        // 1024 nodes per super-bucket
#define POOLROWS 32       // rows per pool block

typedef __attribute__((ext_vector_type(8))) short bf16x8;
typedef __attribute__((ext_vector_type(4))) float f32x4;

__device__ inline unsigned short f2bf(float x) {           // RNE f32 -> bf16
    union { float f; unsigned u; } c; c.f = x;
    unsigned r = (c.u + 0x7FFFu + ((c.u >> 16) & 1u)) >> 16;
    return (unsigned short)r;
}
__device__ inline float bf2f(unsigned u16) {
    union { unsigned u; float f; } c; c.u = (u16 & 0xffffu) << 16; return c.f;
}

// ---- pack 6 weight matrices -> [K/8][64][8] bf16 frags; block 6 zeroes h[N] ----
__global__ void prepack_w(const float* __restrict__ W0, const float* __restrict__ W1,
                          const float* __restrict__ W2, const float* __restrict__ W3,
                          const float* __restrict__ W4, const float* __restrict__ W5,
                          unsigned short* __restrict__ wp,
                          unsigned short* __restrict__ h, int N) {
    const int m = blockIdx.x;
    if (m == 6) {                               // zero dummy row N of h
        for (int i = threadIdx.x; i < 192; i += 256) h[(size_t)N * 192 + i] = 0;
        return;
    }
    const float* W = (m == 0) ? W0 : (m == 1) ? W1 : (m == 2) ? W2
                   : (m == 3) ? W3 : (m == 4) ? W4 : W5;
    const int K = (m < 3) ? 128 : 192;
    unsigned short* o = wp + (size_t)m * 12288;
    for (int idx = threadIdx.x; idx < K * 64; idx += 256) {
        int k = idx >> 6, col = idx & 63;
        o[((k >> 3) * 64 + col) * 8 + (k & 7)] = f2bf(W[idx]);
    }
}

// ---- bf16 MFMA gemm: h[:, g*64..] = in[M,K]@Wg + bg, h bf16. ----
template <int INBF16>
__global__ void gemm_mfma(const void* __restrict__ in_, int M, int K,
                          const unsigned short* __restrict__ wpack,
                          const float* __restrict__ b0, const float* __restrict__ b1,
                          const float* __restrict__ b2, int mslot,
                          unsigned short* __restrict__ h) {
    __shared__ __align__(16) unsigned short Ws[12288];  // K*64 bf16, K<=192
    __shared__ __align__(16) unsigned short As[2048];   // 64 rows x 32 k, swizzled

    const int g = blockIdx.y;
    const float* bias = (g == 0) ? b0 : ((g == 1) ? b1 : b2);
    const unsigned short* wp = wpack + (size_t)(mslot + g) * 12288;

    const int t = threadIdx.x;
    for (int i = t; i < K * 32; i += 256)
        ((int*)Ws)[i] = ((const int*)wp)[i];

    const int m0   = blockIdx.x * 64;
    const int lane = t & 63;
    const int wrow = (t >> 6) * 16;

    const int arow = t >> 2;
    const int aseg = t & 3;
    const int aswz = arow * 32 + ((aseg ^ ((arow >> 1) & 3)) << 3);
    const int grow = m0 + arow;

    const float*          ainf = (const float*)in_ + (size_t)grow * K + aseg * 8;
    const unsigned short* ainb = (const unsigned short*)in_ + (size_t)grow * K + aseg * 8;

    const int lrow = wrow + (lane & 15);
    const int aoff = lrow * 32 + ((((lane >> 4)) ^ ((lrow >> 1) & 3)) << 3);
    const int kq   = lane >> 4;

    f32x4 acc[4] = {};

    const int nsteps = K >> 5;
    for (int s = 0; s < nsteps; ++s) {
        __syncthreads();
        bf16x8 av = {};
        if (grow < M) {
            if (INBF16) {
                av = *reinterpret_cast<const bf16x8*>(ainb + s * 32);
            } else {
                float4 v0 = *reinterpret_cast<const float4*>(ainf + s * 32);
                float4 v1 = *reinterpret_cast<const float4*>(ainf + s * 32 + 4);
                av[0] = (short)f2bf(v0.x); av[1] = (short)f2bf(v0.y);
                av[2] = (short)f2bf(v0.z); av[3] = (short)f2bf(v0.w);
                av[4] = (short)f2bf(v1.x); av[5] = (short)f2bf(v1.y);
                av[6] = (short)f2bf(v1.z); av[7] = (short)f2bf(v1.w);
            }
        }
        *reinterpret_cast<bf16x8*>(&As[aswz]) = av;
        __syncthreads();

        bf16x8 af = *reinterpret_cast<const bf16x8*>(&As[aoff]);
        const int kg = s * 4 + kq;
        #pragma unroll
        for (int n = 0; n < 4; ++n) {
            bf16x8 bfv = *reinterpret_cast<const bf16x8*>(
                &Ws[(size_t)(kg * 64 + n * 16 + (lane & 15)) * 8]);
            acc[n] = __builtin_amdgcn_mfma_f32_16x16x32_bf16(af, bfv, acc[n], 0, 0, 0);
        }
    }

    #pragma unroll
    for (int n = 0; n < 4; ++n) {
        int col = n * 16 + (lane & 15);
        float bv = bias[col];
        #pragma unroll
        for (int r = 0; r < 4; ++r) {
            int row = m0 + wrow + (lane >> 4) * 4 + r;
            if (row < M)
                h[(size_t)row * 192 + g * 64 + col] = f2bf(acc[n][r] + bv);
        }
    }
}

// ---- pass 1: coarse partition into 1024-node super-buckets ----
__global__ void part_coarse(const int* __restrict__ m0, const int* __restrict__ m1,
                            const int* __restrict__ m2, const int* __restrict__ m3,
                            const int* __restrict__ m4, const int* __restrict__ m5,
                            int E, int NSB, int* __restrict__ cnt,
                            unsigned* __restrict__ p1) {
    const int m = blockIdx.y;
    const int* mp = (m == 0) ? m0 : (m == 1) ? m1 : (m == 2) ? m2
                  : (m == 3) ? m3 : (m == 4) ? m4 : m5;
    __shared__ int hist[64];
    __shared__ int base[64];
    const int c0 = blockIdx.x * CHUNK;
    const int t = threadIdx.x;

    int d[EPT]; unsigned srcs[EPT];
    #pragma unroll
    for (int k = 0; k < EPT; ++k) {
        int e = c0 + k * PTHREADS + t;
        bool v = e < E;
        d[k]    = v ? mp[e] : -1;
        srcs[k] = v ? (unsigned)mp[E + e] : 0u;
    }

    if (t < 64) hist[t] = 0;
    __syncthreads();
    #pragma unroll
    for (int k = 0; k < EPT; ++k)
        if (d[k] >= 0) atomicAdd(&hist[d[k] >> SBSHIFT], 1);
    __syncthreads();
    if (t < NSB) {
        int c = hist[t];
        base[t] = (c > 0) ? atomicAdd(&cnt[m * NSB + t], c) : 0;
    }
    __syncthreads();
    if (t < NSB) hist[t] = base[t];
    __syncthreads();
    #pragma unroll
    for (int k = 0; k < EPT; ++k) {
        if (d[k] >= 0) {
            int sb = d[k] >> SBSHIFT;
            int pos = atomicAdd(&hist[sb], 1);
            if (pos < CAPSB)
                p1[(size_t)(m * NSB + sb) * CAPSB + pos] = (srcs[k] << 16) | (unsigned)d[k];
        }
    }
}

// ---- pass 2: per-(SB,map) counting sort -> padded CSR (u16 cols). ----
__global__ void sb_sort(int NSB, int N, const int* __restrict__ cnt,
                        const unsigned* __restrict__ p1,
                        unsigned short* __restrict__ cols, int* __restrict__ rows) {
    const int sb = blockIdx.x;
    const int m  = blockIdx.y;
    __shared__ int bin[1024];
    __shared__ int pend[1024];
    __shared__ int scanbuf[512];
    const int t = threadIdx.x;
    const size_t basep = (size_t)(m * NSB + sb) * CAPSB;
    const size_t basec = (size_t)(m * NSB + sb) * CAPCOL;
    const int c = min(cnt[m * NSB + sb], CAPSB);

    bin[t] = 0; bin[t + 512] = 0;
    __syncthreads();
    for (int i = t; i < c; i += 512)
        atomicAdd(&bin[p1[basep + i] & 1023], 1);
    __syncthreads();

    int b0 = bin[2 * t], b1 = bin[2 * t + 1];
    int p0 = (b0 + 7) & ~7, p1v = (b1 + 7) & ~7;
    int tsum = p0 + p1v;
    scanbuf[t] = tsum;
    __syncthreads();
    for (int off = 1; off < 512; off <<= 1) {
        int v = (t >= off) ? scanbuf[t - off] : 0;
        __syncthreads();
        scanbuf[t] += v;
        __syncthreads();
    }
    int excl = scanbuf[t] - tsum;
    bin[2 * t]      = excl;
    pend[2 * t]     = excl + p0;
    bin[2 * t + 1]  = excl + p0;
    pend[2 * t + 1] = excl + p0 + p1v;
    __syncthreads();

    for (int j = t; j < 1024; j += 512) {
        int n = (sb << SBSHIFT) + j;
        if (n < N) rows[(size_t)m * N + n] = (int)(basec + pend[j]);
    }
    __syncthreads();

    for (int i = t; i < c; i += 512) {
        unsigned r = p1[basep + i];
        int pos = atomicAdd(&bin[r & 1023], 1);
        cols[basec + pos] = (unsigned short)(r >> 16);
    }
    __syncthreads();

    for (int j = t; j < 1024; j += 512) {
        for (int k = bin[j]; k < pend[j]; ++k)
            cols[basec + k] = (unsigned short)N;
    }
}

// ---- two nodes per wave; 16 dword gathers in flight in the main loop. ----
// half-wave edge parity, ushort2 feature pair per lane, shfl_xor(32) merge.
__device__ inline void agg16(const unsigned short* __restrict__ hg,
                             const unsigned short* __restrict__ cols,
                             int i, int hsh, float& ax, float& ay) {
    uint4 ca = *reinterpret_cast<const uint4*>(cols + i);
    uint4 cb = *reinterpret_cast<const uint4*>(cols + i + 8);
    unsigned a0 = (ca.x >> hsh) & 0xffff, a1 = (ca.y >> hsh) & 0xffff;
    unsigned a2 = (ca.z >> hsh) & 0xffff, a3 = (ca.w >> hsh) & 0xffff;
    unsigned b0 = (cb.x >> hsh) & 0xffff, b1 = (cb.y >> hsh) & 0xffff;
    unsigned b2 = (cb.z >> hsh) & 0xffff, b3 = (cb.w >> hsh) & 0xffff;
    unsigned va0 = *reinterpret_cast<const unsigned*>(hg + (size_t)a0 * 192);
    unsigned va1 = *reinterpret_cast<const unsigned*>(hg + (size_t)a1 * 192);
    unsigned va2 = *reinterpret_cast<const unsigned*>(hg + (size_t)a2 * 192);
    unsigned va3 = *reinterpret_cast<const unsigned*>(hg + (size_t)a3 * 192);
    unsigned vb0 = *reinterpret_cast<const unsigned*>(hg + (size_t)b0 * 192);
    unsigned vb1 = *reinterpret_cast<const unsigned*>(hg + (size_t)b1 * 192);
    unsigned vb2 = *reinterpret_cast<const unsigned*>(hg + (size_t)b2 * 192);
    unsigned vb3 = *reinterpret_cast<const unsigned*>(hg + (size_t)b3 * 192);
    ax += ((bf2f(va0) + bf2f(va1)) + (bf2f(va2) + bf2f(va3)))
        + ((bf2f(vb0) + bf2f(vb1)) + (bf2f(vb2) + bf2f(vb3)));
    ay += ((bf2f(va0 >> 16) + bf2f(va1 >> 16)) + (bf2f(va2 >> 16) + bf2f(va3 >> 16)))
        + ((bf2f(vb0 >> 16) + bf2f(vb1 >> 16)) + (bf2f(vb2 >> 16) + bf2f(vb3 >> 16)));
}
__device__ inline void agg8(const unsigned short* __restrict__ hg,
                            const unsigned short* __restrict__ cols,
                            int i, int hsh, float& ax, float& ay) {
    uint4 ca = *reinterpret_cast<const uint4*>(cols + i);
    unsigned a0 = (ca.x >> hsh) & 0xffff, a1 = (ca.y >> hsh) & 0xffff;
    unsigned a2 = (ca.z >> hsh) & 0xffff, a3 = (ca.w >> hsh) & 0xffff;
    unsigned va0 = *reinterpret_cast<const unsigned*>(hg + (size_t)a0 * 192);
    unsigned va1 = *reinterpret_cast<const unsigned*>(hg + (size_t)a1 * 192);
    unsigned va2 = *reinterpret_cast<const unsigned*>(hg + (size_t)a2 * 192);
    unsigned va3 = *reinterpret_cast<const unsigned*>(hg + (size_t)a3 * 192);
    ax += (bf2f(va0) + bf2f(va1)) + (bf2f(va2) + bf2f(va3));
    ay += (bf2f(va0 >> 16) + bf2f(va1 >> 16)) + (bf2f(va2 >> 16) + bf2f(va3 >> 16));
}

__global__ void csr_agg(const unsigned short* __restrict__ h, const int* __restrict__ rows,
                        const unsigned short* __restrict__ cols, int N, int NSB, int mapBase,
                        unsigned short* __restrict__ f) {
    const int g = blockIdx.y;
    const int m = mapBase + g;
    const int lane = threadIdx.x & 63;
    const int hsh = (lane >> 5) * 16;    // 0: even edges, 16: odd edges
    const int fp = (lane & 31) * 2;      // feature pair base
    const int wid = (blockIdx.x * blockDim.x + threadIdx.x) >> 6;
    const int n0 = wid * 2;
    const int n1 = n0 + 1;
    if (n0 >= N) return;
    const bool has1 = (n1 < N);

    const size_t base0 = (size_t)(m * NSB + (n0 >> SBSHIFT)) * CAPCOL;
    int s0 = ((n0 & 1023) == 0) ? (int)base0 : rows[(size_t)m * N + n0 - 1];
    int e0 = rows[(size_t)m * N + n0];
    int s1 = 0, e1 = 0;
    if (has1) {
        s1 = ((n1 & 1023) == 0)
           ? (int)((size_t)(m * NSB + (n1 >> SBSHIFT)) * CAPCOL) : e0;
        e1 = rows[(size_t)m * N + n1];
    }
    const unsigned short* hg = h + g * 64 + fp;

    float ax0 = 0.f, ay0 = 0.f, ax1 = 0.f, ay1 = 0.f;
    int i0 = s0, i1 = s1;

    // dual main loop: 16 edges of each node -> 16 dword gathers in flight
    while (i0 + 16 <= e0 && i1 + 16 <= e1) {
        uint4 ca = *reinterpret_cast<const uint4*>(cols + i0);
        uint4 cb = *reinterpret_cast<const uint4*>(cols + i0 + 8);
        uint4 cc = *reinterpret_cast<const uint4*>(cols + i1);
        uint4 cd = *reinterpret_cast<const uint4*>(cols + i1 + 8);
        unsigned a0 = (ca.x >> hsh) & 0xffff, a1 = (ca.y >> hsh) & 0xffff;
        unsigned a2 = (ca.z >> hsh) & 0xffff, a3 = (ca.w >> hsh) & 0xffff;
        unsigned b0 = (cb.x >> hsh) & 0xffff, b1 = (cb.y >> hsh) & 0xffff;
        unsigned b2 = (cb.z >> hsh) & 0xffff, b3 = (cb.w >> hsh) & 0xffff;
        unsigned c0 = (cc.x >> hsh) & 0xffff, c1 = (cc.y >> hsh) & 0xffff;
        unsigned c2 = (cc.z >> hsh) & 0xffff, c3 = (cc.w >> hsh) & 0xffff;
        unsigned d0 = (cd.x >> hsh) & 0xffff, d1 = (cd.y >> hsh) & 0xffff;
        unsigned d2 = (cd.z >> hsh) & 0xffff, d3 = (cd.w >> hsh) & 0xffff;
        unsigned va0 = *reinterpret_cast<const unsigned*>(hg + (size_t)a0 * 192);
        unsigned va1 = *reinterpret_cast<const unsigned*>(hg + (size_t)a1 * 192);
        unsigned va2 = *reinterpret_cast<const unsigned*>(hg + (size_t)a2 * 192);
        unsigned va3 = *reinterpret_cast<const unsigned*>(hg + (size_t)a3 * 192);
        unsigned vb0 = *reinterpret_cast<const unsigned*>(hg + (size_t)b0 * 192);
        unsigned vb1 = *reinterpret_cast<const unsigned*>(hg + (size_t)b1 * 192);
        unsigned vb2 = *reinterpret_cast<const unsigned*>(hg + (size_t)b2 * 192);
        unsigned vb3 = *reinterpret_cast<const unsigned*>(hg + (size_t)b3 * 192);
        unsigned vc0 = *reinterpret_cast<const unsigned*>(hg + (size_t)c0 * 192);
        unsigned vc1 = *reinterpret_cast<const unsigned*>(hg + (size_t)c1 * 192);
        unsigned vc2 = *reinterpret_cast<const unsigned*>(hg + (size_t)c2 * 192);
        unsigned vc3 = *reinterpret_cast<const unsigned*>(hg + (size_t)c3 * 192);
        unsigned vd0 = *reinterpret_cast<const unsigned*>(hg + (size_t)d0 * 192);
        unsigned vd1 = *reinterpret_cast<const unsigned*>(hg + (size_t)d1 * 192);
        unsigned vd2 = *reinterpret_cast<const unsigned*>(hg + (size_t)d2 * 192);
        unsigned vd3 = *reinterpret_cast<const unsigned*>(hg + (size_t)d3 * 192);
        ax0 += ((bf2f(va0) + bf2f(va1)) + (bf2f(va2) + bf2f(va3)))
             + ((bf2f(vb0) + bf2f(vb1)) + (bf2f(vb2) + bf2f(vb3)));
        ay0 += ((bf2f(va0 >> 16) + bf2f(va1 >> 16)) + (bf2f(va2 >> 16) + bf2f(va3 >> 16)))
             + ((bf2f(vb0 >> 16) + bf2f(vb1 >> 16)) + (bf2f(vb2 >> 16) + bf2f(vb3 >> 16)));
        ax1 += ((bf2f(vc0) + bf2f(vc1)) + (bf2f(vc2) + bf2f(vc3)))
             + ((bf2f(vd0) + bf2f(vd1)) + (bf2f(vd2) + bf2f(vd3)));
        ay1 += ((bf2f(vc0 >> 16) + bf2f(vc1 >> 16)) + (bf2f(vc2 >> 16) + bf2f(vc3 >> 16)))
             + ((bf2f(vd0 >> 16) + bf2f(vd1 >> 16)) + (bf2f(vd2 >> 16) + bf2f(vd3 >> 16)));
        i0 += 16; i1 += 16;
    }
    while (i0 + 16 <= e0) { agg16(hg, cols, i0, hsh, ax0, ay0); i0 += 16; }
    while (i1 + 16 <= e1) { agg16(hg, cols, i1, hsh, ax1, ay1); i1 += 16; }
    if (i0 < e0) agg8(hg, cols, i0, hsh, ax0, ay0);   // runs are x8-padded
    if (i1 < e1) agg8(hg, cols, i1, hsh, ax1, ay1);

    ax0 += __shfl_xor(ax0, 32); ay0 += __shfl_xor(ay0, 32);
    ax1 += __shfl_xor(ax1, 32); ay1 += __shfl_xor(ay1, 32);
    if (hsh == 0) {
        unsigned pk0 = (unsigned)f2bf(fmaxf(ax0, 0.f)) | ((unsigned)f2bf(fmaxf(ay0, 0.f)) << 16);
        *reinterpret_cast<unsigned*>(f + (size_t)n0 * 192 + g * 64 + fp) = pk0;
        if (has1) {
            unsigned pk1 = (unsigned)f2bf(fmaxf(ax1, 0.f)) | ((unsigned)f2bf(fmaxf(ay1, 0.f)) << 16);
            *reinterpret_cast<unsigned*>(f + (size_t)n1 * 192 + g * 64 + fp) = pk1;
        }
    }
}

// segment-pool bf16 f by sorted batch_idx; 32-row chunks for occupancy.
__global__ void pool_kernel(const unsigned short* __restrict__ f, const int* __restrict__ bidx,
                            int N, float* __restrict__ pooled) {
    const int c  = threadIdx.x;          // 0..191
    const int r0 = blockIdx.x * POOLROWS;
    const int r1 = min(r0 + POOLROWS, N);
    if (r0 >= N) return;
    float acc = 0.f;
    int cur = bidx[r0];
    for (int r = r0; r < r1; ++r) {
        int b = bidx[r];
        if (b != cur) {
            atomicAdd(&pooled[(size_t)cur * 192 + c], acc);
            acc = 0.f;
            cur = b;
        }
        acc += bf2f(f[(size_t)r * 192 + c]);
    }
    atomicAdd(&pooled[(size_t)cur * 192 + c], acc);
}

__global__ void mlp_kernel(const float* __restrict__ pooled,
                           const float* __restrict__ A1, const float* __restrict__ ba1,
                           const float* __restrict__ A2, const float* __restrict__ ba2,
                           float* __restrict__ out) {
    __shared__ float p[192];
    __shared__ float hid[256];
    const int b = blockIdx.x;
    const int t = threadIdx.x;
    if (t < 192) p[t] = pooled[(size_t)b * 192 + t];
    __syncthreads();
    float acc = ba1[t];
    for (int k = 0; k < 192; ++k) acc += p[k] * A1[(size_t)k * 256 + t];
    hid[t] = fmaxf(acc, 0.f);
    __syncthreads();
    if (t < 10) {
        float o = ba2[t];
        for (int k = 0; k < 256; ++k) o += hid[k] * A2[(size_t)k * 10 + t];
        out[(size_t)b * 10 + t] = o;
    }
}

extern "C" void kernel_launch(void* const* d_in, const int* in_sizes, int n_in,
                              void* d_out, int out_size, void* d_ws, size_t ws_size,
                              hipStream_t stream) {
    const float* x      = (const float*)d_in[0];
    const int*   map00  = (const int*)d_in[1];
    const int*   map01  = (const int*)d_in[2];
    const int*   map02  = (const int*)d_in[3];
    const int*   map10  = (const int*)d_in[4];
    const int*   map11  = (const int*)d_in[5];
    const int*   map12  = (const int*)d_in[6];
    const int*   bidx   = (const int*)d_in[7];
    const float* W00 = (const float*)d_in[9];  const float* b00 = (const float*)d_in[10];
    const float* W01 = (const float*)d_in[11]; const float* b01 = (const float*)d_in[12];
    const float* W02 = (const float*)d_in[13]; const float* b02 = (const float*)d_in[14];
    const float* W10 = (const float*)d_in[15]; const float* b10 = (const float*)d_in[16];
    const float* W11 = (const float*)d_in[17]; const float* b11 = (const float*)d_in[18];
    const float* W12 = (const float*)d_in[19]; const float* b12 = (const float*)d_in[20];
    const float* A1  = (const float*)d_in[21]; const float* ba1 = (const float*)d_in[22];
    const float* A2  = (const float*)d_in[23]; const float* ba2 = (const float*)d_in[24];

    const int N   = in_sizes[0] / 128;
    const int E   = in_sizes[1] / 2;
    const int NSB = (N + 1023) >> SBSHIFT;     // super-buckets of 1024 nodes

    unsigned short* bufH = (unsigned short*)d_ws;                    // [N+1,192] bf16
    unsigned short* bufF = bufH + (size_t)(N + 1) * 192;             // [N,192] bf16
    float*    pooled = (float*)(bufF + (size_t)N * 192);             // [64,192] f32
    int*      cnt    = (int*)(pooled + 64 * 192);                    // 6*NSB
    unsigned* p1     = (unsigned*)(cnt + 6 * NSB);                   // 6*NSB*CAPSB
    unsigned short* cols = (unsigned short*)(p1 + (size_t)6 * NSB * CAPSB); // +32 slack
    int*      rows   = (int*)(cols + (size_t)6 * NSB * CAPCOL + 32); // 6*N
    unsigned short* wpack = (unsigned short*)(rows + (size_t)6 * N); // 6*12288 bf16

    dim3 gemmGrid((N + 63) / 64, 3);
    dim3 p1Grid((E + CHUNK - 1) / CHUNK, 6);
    dim3 sortGrid(NSB, 6);
    dim3 aggGrid((N + 7) / 8, 3);              // 4 waves/block x 2 nodes/wave

    // build CSR for all 6 maps + pack weights + zero dummy h row up front
    hipMemsetAsync(cnt, 0, (size_t)6 * NSB * sizeof(int), stream);
    prepack_w<<<7, 256, 0, stream>>>(W00, W01, W02, W10, W11, W12, wpack, bufH, N);
    part_coarse<<<p1Grid, PTHREADS, 0, stream>>>(map00, map01, map02,
                                                 map10, map11, map12,
                                                 E, NSB, cnt, p1);
    sb_sort<<<sortGrid, PTHREADS, 0, stream>>>(NSB, N, cnt, p1, cols, rows);
    // layer 0
    gemm_mfma<0><<<gemmGrid, 256, 0, stream>>>(x, N, 128, wpack, b00, b01, b02, 0, bufH);
    csr_agg<<<aggGrid, 256, 0, stream>>>(bufH, rows, cols, N, NSB, 0, bufF);
    // layer 1
    gemm_mfma<1><<<gemmGrid, 256, 0, stream>>>(bufF, N, 192, wpack, b10, b11, b12, 3, bufH);
    csr_agg<<<aggGrid, 256, 0, stream>>>(bufH, rows, cols, N, NSB, 3, bufF);
    // pool + mlp
    hipMemsetAsync(pooled, 0, 64 * 192 * sizeof(float), stream);
    pool_kernel<<<(N + POOLROWS - 1) / POOLROWS, 192, 0, stream>>>(bufF, bidx, N, pooled);
    mlp_kernel<<<64, 256, 0, stream>>>(pooled, A1, ba1, A2, ba2, (float*)d_out);
}

// Round 13
// 226.968 us; speedup vs baseline: 1.8382x; 1.0521x over previous
//
#include <hip/hip_runtime.h>
#include <hip/hip_bf16.h>

// ---------------------------------------------------------------------------
// DHN 2-layer hom-conv GNN.
// Round 13: sb_sort was parallelism-starved (294 blocks, 16% occ, 2 global
// passes over p1). SBSHIFT 10->9 (98 SBs, 588 blocks, half work/block) +
// records staged in LDS (single global read; hist+scatter run from LDS).
// ---------------------------------------------------------------------------

#define CAPSB 9216        // per-(map,SB) p1 capacity: mean 8192 + ~11 sigma
#define CAPCOL 12800      // cols capacity: CAPSB + 512*7 padding
#define CHUNK 4096        // edges per pass-1 block
#define PTHREADS 512
#define EPT 8             // CHUNK / PTHREADS
#define SBSHIFT 9         // 512 nodes per super-bucket
#define POOLROWS 32       // rows per pool block

typedef __attribute__((ext_vector_type(8))) short bf16x8;
typedef __attribute__((ext_vector_type(4))) float f32x4;

__device__ inline unsigned short f2bf(float x) {           // RNE f32 -> bf16
    union { float f; unsigned u; } c; c.f = x;
    unsigned r = (c.u + 0x7FFFu + ((c.u >> 16) & 1u)) >> 16;
    return (unsigned short)r;
}
__device__ inline float bf2f(unsigned u16) {
    union { unsigned u; float f; } c; c.u = (u16 & 0xffffu) << 16; return c.f;
}

// ---- pack 6 weight matrices -> [K/8][64][8] bf16 frags; block 6 zeroes h[N] ----
__global__ void prepack_w(const float* __restrict__ W0, const float* __restrict__ W1,
                          const float* __restrict__ W2, const float* __restrict__ W3,
                          const float* __restrict__ W4, const float* __restrict__ W5,
                          unsigned short* __restrict__ wp,
                          unsigned short* __restrict__ h, int N) {
    const int m = blockIdx.x;
    if (m == 6) {                               // zero dummy row N of h
        for (int i = threadIdx.x; i < 192; i += 256) h[(size_t)N * 192 + i] = 0;
        return;
    }
    const float* W = (m == 0) ? W0 : (m == 1) ? W1 : (m == 2) ? W2
                   : (m == 3) ? W3 : (m == 4) ? W4 : W5;
    const int K = (m < 3) ? 128 : 192;
    unsigned short* o = wp + (size_t)m * 12288;
    for (int idx = threadIdx.x; idx < K * 64; idx += 256) {
        int k = idx >> 6, col = idx & 63;
        o[((k >> 3) * 64 + col) * 8 + (k & 7)] = f2bf(W[idx]);
    }
}

// ---- bf16 MFMA gemm: h[:, g*64..] = in[M,K]@Wg + bg, h bf16. ----
template <int INBF16>
__global__ void gemm_mfma(const void* __restrict__ in_, int M, int K,
                          const unsigned short* __restrict__ wpack,
                          const float* __restrict__ b0, const float* __restrict__ b1,
                          const float* __restrict__ b2, int mslot,
                          unsigned short* __restrict__ h) {
    __shared__ __align__(16) unsigned short Ws[12288];  // K*64 bf16, K<=192
    __shared__ __align__(16) unsigned short As[2048];   // 64 rows x 32 k, swizzled

    const int g = blockIdx.y;
    const float* bias = (g == 0) ? b0 : ((g == 1) ? b1 : b2);
    const unsigned short* wp = wpack + (size_t)(mslot + g) * 12288;

    const int t = threadIdx.x;
    for (int i = t; i < K * 32; i += 256)
        ((int*)Ws)[i] = ((const int*)wp)[i];

    const int m0   = blockIdx.x * 64;
    const int lane = t & 63;
    const int wrow = (t >> 6) * 16;

    const int arow = t >> 2;
    const int aseg = t & 3;
    const int aswz = arow * 32 + ((aseg ^ ((arow >> 1) & 3)) << 3);
    const int grow = m0 + arow;

    const float*          ainf = (const float*)in_ + (size_t)grow * K + aseg * 8;
    const unsigned short* ainb = (const unsigned short*)in_ + (size_t)grow * K + aseg * 8;

    const int lrow = wrow + (lane & 15);
    const int aoff = lrow * 32 + ((((lane >> 4)) ^ ((lrow >> 1) & 3)) << 3);
    const int kq   = lane >> 4;

    f32x4 acc[4] = {};

    const int nsteps = K >> 5;
    for (int s = 0; s < nsteps; ++s) {
        __syncthreads();
        bf16x8 av = {};
        if (grow < M) {
            if (INBF16) {
                av = *reinterpret_cast<const bf16x8*>(ainb + s * 32);
            } else {
                float4 v0 = *reinterpret_cast<const float4*>(ainf + s * 32);
                float4 v1 = *reinterpret_cast<const float4*>(ainf + s * 32 + 4);
                av[0] = (short)f2bf(v0.x); av[1] = (short)f2bf(v0.y);
                av[2] = (short)f2bf(v0.z); av[3] = (short)f2bf(v0.w);
                av[4] = (short)f2bf(v1.x); av[5] = (short)f2bf(v1.y);
                av[6] = (short)f2bf(v1.z); av[7] = (short)f2bf(v1.w);
            }
        }
        *reinterpret_cast<bf16x8*>(&As[aswz]) = av;
        __syncthreads();

        bf16x8 af = *reinterpret_cast<const bf16x8*>(&As[aoff]);
        const int kg = s * 4 + kq;
        #pragma unroll
        for (int n = 0; n < 4; ++n) {
            bf16x8 bfv = *reinterpret_cast<const bf16x8*>(
                &Ws[(size_t)(kg * 64 + n * 16 + (lane & 15)) * 8]);
            acc[n] = __builtin_amdgcn_mfma_f32_16x16x32_bf16(af, bfv, acc[n], 0, 0, 0);
        }
    }

    #pragma unroll
    for (int n = 0; n < 4; ++n) {
        int col = n * 16 + (lane & 15);
        float bv = bias[col];
        #pragma unroll
        for (int r = 0; r < 4; ++r) {
            int row = m0 + wrow + (lane >> 4) * 4 + r;
            if (row < M)
                h[(size_t)row * 192 + g * 64 + col] = f2bf(acc[n][r] + bv);
        }
    }
}

// ---- pass 1: coarse partition into 512-node super-buckets ----
__global__ void part_coarse(const int* __restrict__ m0, const int* __restrict__ m1,
                            const int* __restrict__ m2, const int* __restrict__ m3,
                            const int* __restrict__ m4, const int* __restrict__ m5,
                            int E, int NSB, int* __restrict__ cnt,
                            unsigned* __restrict__ p1) {
    const int m = blockIdx.y;
    const int* mp = (m == 0) ? m0 : (m == 1) ? m1 : (m == 2) ? m2
                  : (m == 3) ? m3 : (m == 4) ? m4 : m5;
    __shared__ int hist[128];
    __shared__ int base[128];
    const int c0 = blockIdx.x * CHUNK;
    const int t = threadIdx.x;

    int d[EPT]; unsigned srcs[EPT];
    #pragma unroll
    for (int k = 0; k < EPT; ++k) {
        int e = c0 + k * PTHREADS + t;
        bool v = e < E;
        d[k]    = v ? mp[e] : -1;
        srcs[k] = v ? (unsigned)mp[E + e] : 0u;
    }

    if (t < 128) hist[t] = 0;
    __syncthreads();
    #pragma unroll
    for (int k = 0; k < EPT; ++k)
        if (d[k] >= 0) atomicAdd(&hist[d[k] >> SBSHIFT], 1);
    __syncthreads();
    if (t < NSB) {
        int c = hist[t];
        base[t] = (c > 0) ? atomicAdd(&cnt[m * NSB + t], c) : 0;
    }
    __syncthreads();
    if (t < NSB) hist[t] = base[t];
    __syncthreads();
    #pragma unroll
    for (int k = 0; k < EPT; ++k) {
        if (d[k] >= 0) {
            int sb = d[k] >> SBSHIFT;
            int pos = atomicAdd(&hist[sb], 1);
            if (pos < CAPSB)
                p1[(size_t)(m * NSB + sb) * CAPSB + pos] = (srcs[k] << 16) | (unsigned)d[k];
        }
    }
}

// ---- pass 2: per-(SB,map) counting sort -> padded CSR (u16 cols). ----
// Records staged in LDS (single global read); 512 bins = 1 per thread.
__global__ void sb_sort(int NSB, int N, const int* __restrict__ cnt,
                        const unsigned* __restrict__ p1,
                        unsigned short* __restrict__ cols, int* __restrict__ rows) {
    const int sb = blockIdx.x;
    const int m  = blockIdx.y;
    __shared__ unsigned rec[CAPSB];
    __shared__ int bin[512];
    __shared__ int pend[512];
    __shared__ int scanbuf[512];
    const int t = threadIdx.x;
    const size_t basep = (size_t)(m * NSB + sb) * CAPSB;
    const size_t basec = (size_t)(m * NSB + sb) * CAPCOL;
    const int c = min(cnt[m * NSB + sb], CAPSB);

    for (int i = t; i < c; i += 512) rec[i] = p1[basep + i];
    bin[t] = 0;
    __syncthreads();
    for (int i = t; i < c; i += 512)
        atomicAdd(&bin[rec[i] & 511], 1);
    __syncthreads();

    // exclusive prefix over padded counts; 1 bin per thread
    int b0 = bin[t];
    int p0 = (b0 + 7) & ~7;
    scanbuf[t] = p0;
    __syncthreads();
    for (int off = 1; off < 512; off <<= 1) {
        int v = (t >= off) ? scanbuf[t - off] : 0;
        __syncthreads();
        scanbuf[t] += v;
        __syncthreads();
    }
    int excl = scanbuf[t] - p0;
    bin[t]  = excl;
    pend[t] = excl + p0;
    __syncthreads();

    // rows[m*N+n] = absolute padded END of node n's run
    {
        int n = (sb << SBSHIFT) + t;
        if (n < N) rows[(size_t)m * N + n] = (int)(basec + pend[t]);
    }
    __syncthreads();

    // scatter srcs (u16) from LDS into owned region
    for (int i = t; i < c; i += 512) {
        unsigned r = rec[i];
        int pos = atomicAdd(&bin[r & 511], 1);
        cols[basec + pos] = (unsigned short)(r >> 16);
    }
    __syncthreads();

    // fill padding with DUMMY = N (zero row of h); max 7 per node
    for (int k = bin[t]; k < pend[t]; ++k)
        cols[basec + k] = (unsigned short)N;
}

// ---- two nodes per wave; 16 dword gathers in flight in the main loop. ----
__device__ inline void agg16(const unsigned short* __restrict__ hg,
                             const unsigned short* __restrict__ cols,
                             int i, int hsh, float& ax, float& ay) {
    uint4 ca = *reinterpret_cast<const uint4*>(cols + i);
    uint4 cb = *reinterpret_cast<const uint4*>(cols + i + 8);
    unsigned a0 = (ca.x >> hsh) & 0xffff, a1 = (ca.y >> hsh) & 0xffff;
    unsigned a2 = (ca.z >> hsh) & 0xffff, a3 = (ca.w >> hsh) & 0xffff;
    unsigned b0 = (cb.x >> hsh) & 0xffff, b1 = (cb.y >> hsh) & 0xffff;
    unsigned b2 = (cb.z >> hsh) & 0xffff, b3 = (cb.w >> hsh) & 0xffff;
    unsigned va0 = *reinterpret_cast<const unsigned*>(hg + (size_t)a0 * 192);
    unsigned va1 = *reinterpret_cast<const unsigned*>(hg + (size_t)a1 * 192);
    unsigned va2 = *reinterpret_cast<const unsigned*>(hg + (size_t)a2 * 192);
    unsigned va3 = *reinterpret_cast<const unsigned*>(hg + (size_t)a3 * 192);
    unsigned vb0 = *reinterpret_cast<const unsigned*>(hg + (size_t)b0 * 192);
    unsigned vb1 = *reinterpret_cast<const unsigned*>(hg + (size_t)b1 * 192);
    unsigned vb2 = *reinterpret_cast<const unsigned*>(hg + (size_t)b2 * 192);
    unsigned vb3 = *reinterpret_cast<const unsigned*>(hg + (size_t)b3 * 192);
    ax += ((bf2f(va0) + bf2f(va1)) + (bf2f(va2) + bf2f(va3)))
        + ((bf2f(vb0) + bf2f(vb1)) + (bf2f(vb2) + bf2f(vb3)));
    ay += ((bf2f(va0 >> 16) + bf2f(va1 >> 16)) + (bf2f(va2 >> 16) + bf2f(va3 >> 16)))
        + ((bf2f(vb0 >> 16) + bf2f(vb1 >> 16)) + (bf2f(vb2 >> 16) + bf2f(vb3 >> 16)));
}
__device__ inline void agg8(const unsigned short* __restrict__ hg,
                            const unsigned short* __restrict__ cols,
                            int i, int hsh, float& ax, float& ay) {
    uint4 ca = *reinterpret_cast<const uint4*>(cols + i);
    unsigned a0 = (ca.x >> hsh) & 0xffff, a1 = (ca.y >> hsh) & 0xffff;
    unsigned a2 = (ca.z >> hsh) & 0xffff, a3 = (ca.w >> hsh) & 0xffff;
    unsigned va0 = *reinterpret_cast<const unsigned*>(hg + (size_t)a0 * 192);
    unsigned va1 = *reinterpret_cast<const unsigned*>(hg + (size_t)a1 * 192);
    unsigned va2 = *reinterpret_cast<const unsigned*>(hg + (size_t)a2 * 192);
    unsigned va3 = *reinterpret_cast<const unsigned*>(hg + (size_t)a3 * 192);
    ax += (bf2f(va0) + bf2f(va1)) + (bf2f(va2) + bf2f(va3));
    ay += (bf2f(va0 >> 16) + bf2f(va1 >> 16)) + (bf2f(va2 >> 16) + bf2f(va3 >> 16));
}

__global__ void csr_agg(const unsigned short* __restrict__ h, const int* __restrict__ rows,
                        const unsigned short* __restrict__ cols, int N, int NSB, int mapBase,
                        unsigned short* __restrict__ f) {
    const int g = blockIdx.y;
    const int m = mapBase + g;
    const int lane = threadIdx.x & 63;
    const int hsh = (lane >> 5) * 16;    // 0: even edges, 16: odd edges
    const int fp = (lane & 31) * 2;      // feature pair base
    const int wid = (blockIdx.x * blockDim.x + threadIdx.x) >> 6;
    const int n0 = wid * 2;
    const int n1 = n0 + 1;
    if (n0 >= N) return;
    const bool has1 = (n1 < N);

    const size_t base0 = (size_t)(m * NSB + (n0 >> SBSHIFT)) * CAPCOL;
    int s0 = ((n0 & 511) == 0) ? (int)base0 : rows[(size_t)m * N + n0 - 1];
    int e0 = rows[(size_t)m * N + n0];
    int s1 = 0, e1 = 0;
    if (has1) {
        s1 = e0;                          // n1 odd -> never SB-start
        e1 = rows[(size_t)m * N + n1];
    }
    const unsigned short* hg = h + g * 64 + fp;

    float ax0 = 0.f, ay0 = 0.f, ax1 = 0.f, ay1 = 0.f;
    int i0 = s0, i1 = s1;

    // dual main loop: 16 edges of each node -> 16 dword gathers in flight
    while (i0 + 16 <= e0 && i1 + 16 <= e1) {
        uint4 ca = *reinterpret_cast<const uint4*>(cols + i0);
        uint4 cb = *reinterpret_cast<const uint4*>(cols + i0 + 8);
        uint4 cc = *reinterpret_cast<const uint4*>(cols + i1);
        uint4 cd = *reinterpret_cast<const uint4*>(cols + i1 + 8);
        unsigned a0 = (ca.x >> hsh) & 0xffff, a1 = (ca.y >> hsh) & 0xffff;
        unsigned a2 = (ca.z >> hsh) & 0xffff, a3 = (ca.w >> hsh) & 0xffff;
        unsigned b0 = (cb.x >> hsh) & 0xffff, b1 = (cb.y >> hsh) & 0xffff;
        unsigned b2 = (cb.z >> hsh) & 0xffff, b3 = (cb.w >> hsh) & 0xffff;
        unsigned c0 = (cc.x >> hsh) & 0xffff, c1 = (cc.y >> hsh) & 0xffff;
        unsigned c2 = (cc.z >> hsh) & 0xffff, c3 = (cc.w >> hsh) & 0xffff;
        unsigned d0 = (cd.x >> hsh) & 0xffff, d1 = (cd.y >> hsh) & 0xffff;
        unsigned d2 = (cd.z >> hsh) & 0xffff, d3 = (cd.w >> hsh) & 0xffff;
        unsigned va0 = *reinterpret_cast<const unsigned*>(hg + (size_t)a0 * 192);
        unsigned va1 = *reinterpret_cast<const unsigned*>(hg + (size_t)a1 * 192);
        unsigned va2 = *reinterpret_cast<const unsigned*>(hg + (size_t)a2 * 192);
        unsigned va3 = *reinterpret_cast<const unsigned*>(hg + (size_t)a3 * 192);
        unsigned vb0 = *reinterpret_cast<const unsigned*>(hg + (size_t)b0 * 192);
        unsigned vb1 = *reinterpret_cast<const unsigned*>(hg + (size_t)b1 * 192);
        unsigned vb2 = *reinterpret_cast<const unsigned*>(hg + (size_t)b2 * 192);
        unsigned vb3 = *reinterpret_cast<const unsigned*>(hg + (size_t)b3 * 192);
        unsigned vc0 = *reinterpret_cast<const unsigned*>(hg + (size_t)c0 * 192);
        unsigned vc1 = *reinterpret_cast<const unsigned*>(hg + (size_t)c1 * 192);
        unsigned vc2 = *reinterpret_cast<const unsigned*>(hg + (size_t)c2 * 192);
        unsigned vc3 = *reinterpret_cast<const unsigned*>(hg + (size_t)c3 * 192);
        unsigned vd0 = *reinterpret_cast<const unsigned*>(hg + (size_t)d0 * 192);
        unsigned vd1 = *reinterpret_cast<const unsigned*>(hg + (size_t)d1 * 192);
        unsigned vd2 = *reinterpret_cast<const unsigned*>(hg + (size_t)d2 * 192);
        unsigned vd3 = *reinterpret_cast<const unsigned*>(hg + (size_t)d3 * 192);
        ax0 += ((bf2f(va0) + bf2f(va1)) + (bf2f(va2) + bf2f(va3)))
             + ((bf2f(vb0) + bf2f(vb1)) + (bf2f(vb2) + bf2f(vb3)));
        ay0 += ((bf2f(va0 >> 16) + bf2f(va1 >> 16)) + (bf2f(va2 >> 16) + bf2f(va3 >> 16)))
             + ((bf2f(vb0 >> 16) + bf2f(vb1 >> 16)) + (bf2f(vb2 >> 16) + bf2f(vb3 >> 16)));
        ax1 += ((bf2f(vc0) + bf2f(vc1)) + (bf2f(vc2) + bf2f(vc3)))
             + ((bf2f(vd0) + bf2f(vd1)) + (bf2f(vd2) + bf2f(vd3)));
        ay1 += ((bf2f(vc0 >> 16) + bf2f(vc1 >> 16)) + (bf2f(vc2 >> 16) + bf2f(vc3 >> 16)))
             + ((bf2f(vd0 >> 16) + bf2f(vd1 >> 16)) + (bf2f(vd2 >> 16) + bf2f(vd3 >> 16)));
        i0 += 16; i1 += 16;
    }
    while (i0 + 16 <= e0) { agg16(hg, cols, i0, hsh, ax0, ay0); i0 += 16; }
    while (i1 + 16 <= e1) { agg16(hg, cols, i1, hsh, ax1, ay1); i1 += 16; }
    if (i0 < e0) agg8(hg, cols, i0, hsh, ax0, ay0);   // runs are x8-padded
    if (i1 < e1) agg8(hg, cols, i1, hsh, ax1, ay1);

    ax0 += __shfl_xor(ax0, 32); ay0 += __shfl_xor(ay0, 32);
    ax1 += __shfl_xor(ax1, 32); ay1 += __shfl_xor(ay1, 32);
    if (hsh == 0) {
        unsigned pk0 = (unsigned)f2bf(fmaxf(ax0, 0.f)) | ((unsigned)f2bf(fmaxf(ay0, 0.f)) << 16);
        *reinterpret_cast<unsigned*>(f + (size_t)n0 * 192 + g * 64 + fp) = pk0;
        if (has1) {
            unsigned pk1 = (unsigned)f2bf(fmaxf(ax1, 0.f)) | ((unsigned)f2bf(fmaxf(ay1, 0.f)) << 16);
            *reinterpret_cast<unsigned*>(f + (size_t)n1 * 192 + g * 64 + fp) = pk1;
        }
    }
}

// segment-pool bf16 f by sorted batch_idx; 32-row chunks for occupancy.
__global__ void pool_kernel(const unsigned short* __restrict__ f, const int* __restrict__ bidx,
                            int N, float* __restrict__ pooled) {
    const int c  = threadIdx.x;          // 0..191
    const int r0 = blockIdx.x * POOLROWS;
    const int r1 = min(r0 + POOLROWS, N);
    if (r0 >= N) return;
    float acc = 0.f;
    int cur = bidx[r0];
    for (int r = r0; r < r1; ++r) {
        int b = bidx[r];
        if (b != cur) {
            atomicAdd(&pooled[(size_t)cur * 192 + c], acc);
            acc = 0.f;
            cur = b;
        }
        acc += bf2f(f[(size_t)r * 192 + c]);
    }
    atomicAdd(&pooled[(size_t)cur * 192 + c], acc);
}

__global__ void mlp_kernel(const float* __restrict__ pooled,
                           const float* __restrict__ A1, const float* __restrict__ ba1,
                           const float* __restrict__ A2, const float* __restrict__ ba2,
                           float* __restrict__ out) {
    __shared__ float p[192];
    __shared__ float hid[256];
    const int b = blockIdx.x;
    const int t = threadIdx.x;
    if (t < 192) p[t] = pooled[(size_t)b * 192 + t];
    __syncthreads();
    float acc = ba1[t];
    for (int k = 0; k < 192; ++k) acc += p[k] * A1[(size_t)k * 256 + t];
    hid[t] = fmaxf(acc, 0.f);
    __syncthreads();
    if (t < 10) {
        float o = ba2[t];
        for (int k = 0; k < 256; ++k) o += hid[k] * A2[(size_t)k * 10 + t];
        out[(size_t)b * 10 + t] = o;
    }
}

extern "C" void kernel_launch(void* const* d_in, const int* in_sizes, int n_in,
                              void* d_out, int out_size, void* d_ws, size_t ws_size,
                              hipStream_t stream) {
    const float* x      = (const float*)d_in[0];
    const int*   map00  = (const int*)d_in[1];
    const int*   map01  = (const int*)d_in[2];
    const int*   map02  = (const int*)d_in[3];
    const int*   map10  = (const int*)d_in[4];
    const int*   map11  = (const int*)d_in[5];
    const int*   map12  = (const int*)d_in[6];
    const int*   bidx   = (const int*)d_in[7];
    const float* W00 = (const float*)d_in[9];  const float* b00 = (const float*)d_in[10];
    const float* W01 = (const float*)d_in[11]; const float* b01 = (const float*)d_in[12];
    const float* W02 = (const float*)d_in[13]; const float* b02 = (const float*)d_in[14];
    const float* W10 = (const float*)d_in[15]; const float* b10 = (const float*)d_in[16];
    const float* W11 = (const float*)d_in[17]; const float* b11 = (const float*)d_in[18];
    const float* W12 = (const float*)d_in[19]; const float* b12 = (const float*)d_in[20];
    const float* A1  = (const float*)d_in[21]; const float* ba1 = (const float*)d_in[22];
    const float* A2  = (const float*)d_in[23]; const float* ba2 = (const float*)d_in[24];

    const int N   = in_sizes[0] / 128;
    const int E   = in_sizes[1] / 2;
    const int NSB = (N + 511) >> SBSHIFT;      // 98 super-buckets of 512 nodes

    unsigned short* bufH = (unsigned short*)d_ws;                    // [N+1,192] bf16
    unsigned short* bufF = bufH + (size_t)(N + 1) * 192;             // [N,192] bf16
    float*    pooled = (float*)(bufF + (size_t)N * 192);             // [64,192] f32
    int*      cnt    = (int*)(pooled + 64 * 192);                    // 6*NSB
    unsigned* p1     = (unsigned*)(cnt + 6 * NSB);                   // 6*NSB*CAPSB
    unsigned short* cols = (unsigned short*)(p1 + (size_t)6 * NSB * CAPSB); // +32 slack
    int*      rows   = (int*)(cols + (size_t)6 * NSB * CAPCOL + 32); // 6*N
    unsigned short* wpack = (unsigned short*)(rows + (size_t)6 * N); // 6*12288 bf16

    dim3 gemmGrid((N + 63) / 64, 3);
    dim3 p1Grid((E + CHUNK - 1) / CHUNK, 6);
    dim3 sortGrid(NSB, 6);
    dim3 aggGrid((N + 7) / 8, 3);              // 4 waves/block x 2 nodes/wave

    // build CSR for all 6 maps + pack weights + zero dummy h row up front
    hipMemsetAsync(cnt, 0, (size_t)6 * NSB * sizeof(int), stream);
    prepack_w<<<7, 256, 0, stream>>>(W00, W01, W02, W10, W11, W12, wpack, bufH, N);
    part_coarse<<<p1Grid, PTHREADS, 0, stream>>>(map00, map01, map02,
                                                 map10, map11, map12,
                                                 E, NSB, cnt, p1);
    sb_sort<<<sortGrid, PTHREADS, 0, stream>>>(NSB, N, cnt, p1, cols, rows);
    // layer 0
    gemm_mfma<0><<<gemmGrid, 256, 0, stream>>>(x, N, 128, wpack, b00, b01, b02, 0, bufH);
    csr_agg<<<aggGrid, 256, 0, stream>>>(bufH, rows, cols, N, NSB, 0, bufF);
    // layer 1
    gemm_mfma<1><<<gemmGrid, 256, 0, stream>>>(bufF, N, 192, wpack, b10, b11, b12, 3, bufH);
    csr_agg<<<aggGrid, 256, 0, stream>>>(bufH, rows, cols, N, NSB, 3, bufF);
    // pool + mlp
    hipMemsetAsync(pooled, 0, 64 * 192 * sizeof(float), stream);
    pool_kernel<<<(N + POOLROWS - 1) / POOLROWS, 192, 0, stream>>>(bufF, bidx, N, pooled);
    mlp_kernel<<<64, 256, 0, stream>>>(pooled, A1, ba1, A2, ba2, (float*)d_out);
}

// Round 14
// 208.827 us; speedup vs baseline: 1.9978x; 1.0869x over previous
//
#include <hip/hip_runtime.h>
#include <hip/hip_bf16.h>

// ---------------------------------------------------------------------------
// DHN 2-layer hom-conv GNN.
// Round 14: part_coarse wrote 2.4M isolated 4B records (2.3x write amp,
// 64 lines touched per wave-instr). Now: LDS-stage records ordered by SB
// (128-bin scan for local offsets), then copy out linearly -> coalesced
// per-SB runs. Rider: cnt/pooled memsets folded into prepack_w (2 fill
// dispatches leave the graph).
// ---------------------------------------------------------------------------

#define CAPSB 9216        // per-(map,SB) p1 capacity: mean 8192 + ~11 sigma
#define CAPCOL 12800      // cols capacity: CAPSB + 512*7 padding
#define CHUNK 4096        // edges per pass-1 block
#define PTHREADS 512
#define EPT 8             // CHUNK / PTHREADS
#define SBSHIFT 9         // 512 nodes per super-bucket
#define POOLROWS 32       // rows per pool block

typedef __attribute__((ext_vector_type(8))) short bf16x8;
typedef __attribute__((ext_vector_type(4))) float f32x4;

__device__ inline unsigned short f2bf(float x) {           // RNE f32 -> bf16
    union { float f; unsigned u; } c; c.f = x;
    unsigned r = (c.u + 0x7FFFu + ((c.u >> 16) & 1u)) >> 16;
    return (unsigned short)r;
}
__device__ inline float bf2f(unsigned u16) {
    union { unsigned u; float f; } c; c.u = (u16 & 0xffffu) << 16; return c.f;
}

// ---- pack 6 weight matrices -> [K/8][64][8] bf16 frags.
// block 6: zero h dummy row N + cnt (6*NSB) + pooled (64*192).
__global__ void prepack_w(const float* __restrict__ W0, const float* __restrict__ W1,
                          const float* __restrict__ W2, const float* __restrict__ W3,
                          const float* __restrict__ W4, const float* __restrict__ W5,
                          unsigned short* __restrict__ wp,
                          unsigned short* __restrict__ h, int N,
                          int* __restrict__ cnt, int NSB,
                          float* __restrict__ pooled) {
    const int m = blockIdx.x;
    if (m == 6) {
        for (int i = threadIdx.x; i < 192; i += 256) h[(size_t)N * 192 + i] = 0;
        for (int i = threadIdx.x; i < 6 * NSB; i += 256) cnt[i] = 0;
        for (int i = threadIdx.x; i < 64 * 192; i += 256) pooled[i] = 0.f;
        return;
    }
    const float* W = (m == 0) ? W0 : (m == 1) ? W1 : (m == 2) ? W2
                   : (m == 3) ? W3 : (m == 4) ? W4 : W5;
    const int K = (m < 3) ? 128 : 192;
    unsigned short* o = wp + (size_t)m * 12288;
    for (int idx = threadIdx.x; idx < K * 64; idx += 256) {
        int k = idx >> 6, col = idx & 63;
        o[((k >> 3) * 64 + col) * 8 + (k & 7)] = f2bf(W[idx]);
    }
}

// ---- bf16 MFMA gemm: h[:, g*64..] = in[M,K]@Wg + bg, h bf16. ----
template <int INBF16>
__global__ void gemm_mfma(const void* __restrict__ in_, int M, int K,
                          const unsigned short* __restrict__ wpack,
                          const float* __restrict__ b0, const float* __restrict__ b1,
                          const float* __restrict__ b2, int mslot,
                          unsigned short* __restrict__ h) {
    __shared__ __align__(16) unsigned short Ws[12288];  // K*64 bf16, K<=192
    __shared__ __align__(16) unsigned short As[2048];   // 64 rows x 32 k, swizzled

    const int g = blockIdx.y;
    const float* bias = (g == 0) ? b0 : ((g == 1) ? b1 : b2);
    const unsigned short* wp = wpack + (size_t)(mslot + g) * 12288;

    const int t = threadIdx.x;
    for (int i = t; i < K * 32; i += 256)
        ((int*)Ws)[i] = ((const int*)wp)[i];

    const int m0   = blockIdx.x * 64;
    const int lane = t & 63;
    const int wrow = (t >> 6) * 16;

    const int arow = t >> 2;
    const int aseg = t & 3;
    const int aswz = arow * 32 + ((aseg ^ ((arow >> 1) & 3)) << 3);
    const int grow = m0 + arow;

    const float*          ainf = (const float*)in_ + (size_t)grow * K + aseg * 8;
    const unsigned short* ainb = (const unsigned short*)in_ + (size_t)grow * K + aseg * 8;

    const int lrow = wrow + (lane & 15);
    const int aoff = lrow * 32 + ((((lane >> 4)) ^ ((lrow >> 1) & 3)) << 3);
    const int kq   = lane >> 4;

    f32x4 acc[4] = {};

    const int nsteps = K >> 5;
    for (int s = 0; s < nsteps; ++s) {
        __syncthreads();
        bf16x8 av = {};
        if (grow < M) {
            if (INBF16) {
                av = *reinterpret_cast<const bf16x8*>(ainb + s * 32);
            } else {
                float4 v0 = *reinterpret_cast<const float4*>(ainf + s * 32);
                float4 v1 = *reinterpret_cast<const float4*>(ainf + s * 32 + 4);
                av[0] = (short)f2bf(v0.x); av[1] = (short)f2bf(v0.y);
                av[2] = (short)f2bf(v0.z); av[3] = (short)f2bf(v0.w);
                av[4] = (short)f2bf(v1.x); av[5] = (short)f2bf(v1.y);
                av[6] = (short)f2bf(v1.z); av[7] = (short)f2bf(v1.w);
            }
        }
        *reinterpret_cast<bf16x8*>(&As[aswz]) = av;
        __syncthreads();

        bf16x8 af = *reinterpret_cast<const bf16x8*>(&As[aoff]);
        const int kg = s * 4 + kq;
        #pragma unroll
        for (int n = 0; n < 4; ++n) {
            bf16x8 bfv = *reinterpret_cast<const bf16x8*>(
                &Ws[(size_t)(kg * 64 + n * 16 + (lane & 15)) * 8]);
            acc[n] = __builtin_amdgcn_mfma_f32_16x16x32_bf16(af, bfv, acc[n], 0, 0, 0);
        }
    }

    #pragma unroll
    for (int n = 0; n < 4; ++n) {
        int col = n * 16 + (lane & 15);
        float bv = bias[col];
        #pragma unroll
        for (int r = 0; r < 4; ++r) {
            int row = m0 + wrow + (lane >> 4) * 4 + r;
            if (row < M)
                h[(size_t)row * 192 + g * 64 + col] = f2bf(acc[n][r] + bv);
        }
    }
}

// ---- pass 1: coarse partition into 512-node super-buckets. ----
// Records LDS-staged ordered by SB, then copied out linearly (coalesced runs).
__global__ void part_coarse(const int* __restrict__ m0, const int* __restrict__ m1,
                            const int* __restrict__ m2, const int* __restrict__ m3,
                            const int* __restrict__ m4, const int* __restrict__ m5,
                            int E, int NSB, int* __restrict__ cnt,
                            unsigned* __restrict__ p1) {
    const int m = blockIdx.y;
    const int* mp = (m == 0) ? m0 : (m == 1) ? m1 : (m == 2) ? m2
                  : (m == 3) ? m3 : (m == 4) ? m4 : m5;
    __shared__ int hist[128];
    __shared__ int scanb[128];
    __shared__ int loff[128];
    __shared__ int delta[128];
    __shared__ unsigned stage[CHUNK];     // 16 KB
    const int c0 = blockIdx.x * CHUNK;
    const int t = threadIdx.x;

    int d[EPT]; unsigned srcs[EPT];
    #pragma unroll
    for (int k = 0; k < EPT; ++k) {
        int e = c0 + k * PTHREADS + t;
        bool v = e < E;
        d[k]    = v ? mp[e] : -1;
        srcs[k] = v ? (unsigned)mp[E + e] : 0u;
    }

    if (t < 128) hist[t] = 0;
    __syncthreads();
    #pragma unroll
    for (int k = 0; k < EPT; ++k)
        if (d[k] >= 0) atomicAdd(&hist[d[k] >> SBSHIFT], 1);
    __syncthreads();

    // inclusive scan over 128 bins (threads 0..127)
    if (t < 128) scanb[t] = hist[t];
    __syncthreads();
    for (int off = 1; off < 128; off <<= 1) {
        int v = (t < 128 && t >= off) ? scanb[t - off] : 0;
        __syncthreads();
        if (t < 128) scanb[t] += v;
        __syncthreads();
    }
    // claim global ranges; delta maps staged index -> absolute p1 index
    if (t < NSB) {
        int c = hist[t];
        int lstart = scanb[t] - c;
        int gbase = (c > 0) ? atomicAdd(&cnt[m * NSB + t], c) : 0;
        loff[t]  = lstart;
        delta[t] = (m * NSB + t) * CAPSB + gbase - lstart;
    }
    __syncthreads();

    // LDS scatter (ordered by SB)
    #pragma unroll
    for (int k = 0; k < EPT; ++k) {
        if (d[k] >= 0) {
            int sb = d[k] >> SBSHIFT;
            int pos = atomicAdd(&loff[sb], 1);
            stage[pos] = (srcs[k] << 16) | (unsigned)d[k];
        }
    }
    __syncthreads();

    // linear copy-out: consecutive i in an SB run -> consecutive global addrs
    const int total = scanb[127];
    for (int i = t; i < total; i += PTHREADS) {
        unsigned r = stage[i];
        int sb = (r & 0xffffu) >> SBSHIFT;
        int gidx = delta[sb] + i;
        if (gidx - (m * NSB + sb) * CAPSB < CAPSB)
            p1[gidx] = r;
    }
}

// ---- pass 2: per-(SB,map) counting sort -> padded CSR (u16 cols). ----
__global__ void sb_sort(int NSB, int N, const int* __restrict__ cnt,
                        const unsigned* __restrict__ p1,
                        unsigned short* __restrict__ cols, int* __restrict__ rows) {
    const int sb = blockIdx.x;
    const int m  = blockIdx.y;
    __shared__ unsigned rec[CAPSB];
    __shared__ int bin[512];
    __shared__ int pend[512];
    __shared__ int scanbuf[512];
    const int t = threadIdx.x;
    const size_t basep = (size_t)(m * NSB + sb) * CAPSB;
    const size_t basec = (size_t)(m * NSB + sb) * CAPCOL;
    const int c = min(cnt[m * NSB + sb], CAPSB);

    for (int i = t; i < c; i += 512) rec[i] = p1[basep + i];
    bin[t] = 0;
    __syncthreads();
    for (int i = t; i < c; i += 512)
        atomicAdd(&bin[rec[i] & 511], 1);
    __syncthreads();

    int b0 = bin[t];
    int p0 = (b0 + 7) & ~7;
    scanbuf[t] = p0;
    __syncthreads();
    for (int off = 1; off < 512; off <<= 1) {
        int v = (t >= off) ? scanbuf[t - off] : 0;
        __syncthreads();
        scanbuf[t] += v;
        __syncthreads();
    }
    int excl = scanbuf[t] - p0;
    bin[t]  = excl;
    pend[t] = excl + p0;
    __syncthreads();

    {
        int n = (sb << SBSHIFT) + t;
        if (n < N) rows[(size_t)m * N + n] = (int)(basec + pend[t]);
    }
    __syncthreads();

    for (int i = t; i < c; i += 512) {
        unsigned r = rec[i];
        int pos = atomicAdd(&bin[r & 511], 1);
        cols[basec + pos] = (unsigned short)(r >> 16);
    }
    __syncthreads();

    for (int k = bin[t]; k < pend[t]; ++k)
        cols[basec + k] = (unsigned short)N;
}

// ---- two nodes per wave; 16 dword gathers in flight in the main loop. ----
__device__ inline void agg16(const unsigned short* __restrict__ hg,
                             const unsigned short* __restrict__ cols,
                             int i, int hsh, float& ax, float& ay) {
    uint4 ca = *reinterpret_cast<const uint4*>(cols + i);
    uint4 cb = *reinterpret_cast<const uint4*>(cols + i + 8);
    unsigned a0 = (ca.x >> hsh) & 0xffff, a1 = (ca.y >> hsh) & 0xffff;
    unsigned a2 = (ca.z >> hsh) & 0xffff, a3 = (ca.w >> hsh) & 0xffff;
    unsigned b0 = (cb.x >> hsh) & 0xffff, b1 = (cb.y >> hsh) & 0xffff;
    unsigned b2 = (cb.z >> hsh) & 0xffff, b3 = (cb.w >> hsh) & 0xffff;
    unsigned va0 = *reinterpret_cast<const unsigned*>(hg + (size_t)a0 * 192);
    unsigned va1 = *reinterpret_cast<const unsigned*>(hg + (size_t)a1 * 192);
    unsigned va2 = *reinterpret_cast<const unsigned*>(hg + (size_t)a2 * 192);
    unsigned va3 = *reinterpret_cast<const unsigned*>(hg + (size_t)a3 * 192);
    unsigned vb0 = *reinterpret_cast<const unsigned*>(hg + (size_t)b0 * 192);
    unsigned vb1 = *reinterpret_cast<const unsigned*>(hg + (size_t)b1 * 192);
    unsigned vb2 = *reinterpret_cast<const unsigned*>(hg + (size_t)b2 * 192);
    unsigned vb3 = *reinterpret_cast<const unsigned*>(hg + (size_t)b3 * 192);
    ax += ((bf2f(va0) + bf2f(va1)) + (bf2f(va2) + bf2f(va3)))
        + ((bf2f(vb0) + bf2f(vb1)) + (bf2f(vb2) + bf2f(vb3)));
    ay += ((bf2f(va0 >> 16) + bf2f(va1 >> 16)) + (bf2f(va2 >> 16) + bf2f(va3 >> 16)))
        + ((bf2f(vb0 >> 16) + bf2f(vb1 >> 16)) + (bf2f(vb2 >> 16) + bf2f(vb3 >> 16)));
}
__device__ inline void agg8(const unsigned short* __restrict__ hg,
                            const unsigned short* __restrict__ cols,
                            int i, int hsh, float& ax, float& ay) {
    uint4 ca = *reinterpret_cast<const uint4*>(cols + i);
    unsigned a0 = (ca.x >> hsh) & 0xffff, a1 = (ca.y >> hsh) & 0xffff;
    unsigned a2 = (ca.z >> hsh) & 0xffff, a3 = (ca.w >> hsh) & 0xffff;
    unsigned va0 = *reinterpret_cast<const unsigned*>(hg + (size_t)a0 * 192);
    unsigned va1 = *reinterpret_cast<const unsigned*>(hg + (size_t)a1 * 192);
    unsigned va2 = *reinterpret_cast<const unsigned*>(hg + (size_t)a2 * 192);
    unsigned va3 = *reinterpret_cast<const unsigned*>(hg + (size_t)a3 * 192);
    ax += (bf2f(va0) + bf2f(va1)) + (bf2f(va2) + bf2f(va3));
    ay += (bf2f(va0 >> 16) + bf2f(va1 >> 16)) + (bf2f(va2 >> 16) + bf2f(va3 >> 16));
}

__global__ void csr_agg(const unsigned short* __restrict__ h, const int* __restrict__ rows,
                        const unsigned short* __restrict__ cols, int N, int NSB, int mapBase,
                        unsigned short* __restrict__ f) {
    const int g = blockIdx.y;
    const int m = mapBase + g;
    const int lane = threadIdx.x & 63;
    const int hsh = (lane >> 5) * 16;    // 0: even edges, 16: odd edges
    const int fp = (lane & 31) * 2;      // feature pair base
    const int wid = (blockIdx.x * blockDim.x + threadIdx.x) >> 6;
    const int n0 = wid * 2;
    const int n1 = n0 + 1;
    if (n0 >= N) return;
    const bool has1 = (n1 < N);

    const size_t base0 = (size_t)(m * NSB + (n0 >> SBSHIFT)) * CAPCOL;
    int s0 = ((n0 & 511) == 0) ? (int)base0 : rows[(size_t)m * N + n0 - 1];
    int e0 = rows[(size_t)m * N + n0];
    int s1 = 0, e1 = 0;
    if (has1) {
        s1 = e0;                          // n1 odd -> never SB-start
        e1 = rows[(size_t)m * N + n1];
    }
    const unsigned short* hg = h + g * 64 + fp;

    float ax0 = 0.f, ay0 = 0.f, ax1 = 0.f, ay1 = 0.f;
    int i0 = s0, i1 = s1;

    while (i0 + 16 <= e0 && i1 + 16 <= e1) {
        uint4 ca = *reinterpret_cast<const uint4*>(cols + i0);
        uint4 cb = *reinterpret_cast<const uint4*>(cols + i0 + 8);
        uint4 cc = *reinterpret_cast<const uint4*>(cols + i1);
        uint4 cd = *reinterpret_cast<const uint4*>(cols + i1 + 8);
        unsigned a0 = (ca.x >> hsh) & 0xffff, a1 = (ca.y >> hsh) & 0xffff;
        unsigned a2 = (ca.z >> hsh) & 0xffff, a3 = (ca.w >> hsh) & 0xffff;
        unsigned b0 = (cb.x >> hsh) & 0xffff, b1 = (cb.y >> hsh) & 0xffff;
        unsigned b2 = (cb.z >> hsh) & 0xffff, b3 = (cb.w >> hsh) & 0xffff;
        unsigned c0 = (cc.x >> hsh) & 0xffff, c1 = (cc.y >> hsh) & 0xffff;
        unsigned c2 = (cc.z >> hsh) & 0xffff, c3 = (cc.w >> hsh) & 0xffff;
        unsigned d0 = (cd.x >> hsh) & 0xffff, d1 = (cd.y >> hsh) & 0xffff;
        unsigned d2 = (cd.z >> hsh) & 0xffff, d3 = (cd.w >> hsh) & 0xffff;
        unsigned va0 = *reinterpret_cast<const unsigned*>(hg + (size_t)a0 * 192);
        unsigned va1 = *reinterpret_cast<const unsigned*>(hg + (size_t)a1 * 192);
        unsigned va2 = *reinterpret_cast<const unsigned*>(hg + (size_t)a2 * 192);
        unsigned va3 = *reinterpret_cast<const unsigned*>(hg + (size_t)a3 * 192);
        unsigned vb0 = *reinterpret_cast<const unsigned*>(hg + (size_t)b0 * 192);
        unsigned vb1 = *reinterpret_cast<const unsigned*>(hg + (size_t)b1 * 192);
        unsigned vb2 = *reinterpret_cast<const unsigned*>(hg + (size_t)b2 * 192);
        unsigned vb3 = *reinterpret_cast<const unsigned*>(hg + (size_t)b3 * 192);
        unsigned vc0 = *reinterpret_cast<const unsigned*>(hg + (size_t)c0 * 192);
        unsigned vc1 = *reinterpret_cast<const unsigned*>(hg + (size_t)c1 * 192);
        unsigned vc2 = *reinterpret_cast<const unsigned*>(hg + (size_t)c2 * 192);
        unsigned vc3 = *reinterpret_cast<const unsigned*>(hg + (size_t)c3 * 192);
        unsigned vd0 = *reinterpret_cast<const unsigned*>(hg + (size_t)d0 * 192);
        unsigned vd1 = *reinterpret_cast<const unsigned*>(hg + (size_t)d1 * 192);
        unsigned vd2 = *reinterpret_cast<const unsigned*>(hg + (size_t)d2 * 192);
        unsigned vd3 = *reinterpret_cast<const unsigned*>(hg + (size_t)d3 * 192);
        ax0 += ((bf2f(va0) + bf2f(va1)) + (bf2f(va2) + bf2f(va3)))
             + ((bf2f(vb0) + bf2f(vb1)) + (bf2f(vb2) + bf2f(vb3)));
        ay0 += ((bf2f(va0 >> 16) + bf2f(va1 >> 16)) + (bf2f(va2 >> 16) + bf2f(va3 >> 16)))
             + ((bf2f(vb0 >> 16) + bf2f(vb1 >> 16)) + (bf2f(vb2 >> 16) + bf2f(vb3 >> 16)));
        ax1 += ((bf2f(vc0) + bf2f(vc1)) + (bf2f(vc2) + bf2f(vc3)))
             + ((bf2f(vd0) + bf2f(vd1)) + (bf2f(vd2) + bf2f(vd3)));
        ay1 += ((bf2f(vc0 >> 16) + bf2f(vc1 >> 16)) + (bf2f(vc2 >> 16) + bf2f(vc3 >> 16)))
             + ((bf2f(vd0 >> 16) + bf2f(vd1 >> 16)) + (bf2f(vd2 >> 16) + bf2f(vd3 >> 16)));
        i0 += 16; i1 += 16;
    }
    while (i0 + 16 <= e0) { agg16(hg, cols, i0, hsh, ax0, ay0); i0 += 16; }
    while (i1 + 16 <= e1) { agg16(hg, cols, i1, hsh, ax1, ay1); i1 += 16; }
    if (i0 < e0) agg8(hg, cols, i0, hsh, ax0, ay0);   // runs are x8-padded
    if (i1 < e1) agg8(hg, cols, i1, hsh, ax1, ay1);

    ax0 += __shfl_xor(ax0, 32); ay0 += __shfl_xor(ay0, 32);
    ax1 += __shfl_xor(ax1, 32); ay1 += __shfl_xor(ay1, 32);
    if (hsh == 0) {
        unsigned pk0 = (unsigned)f2bf(fmaxf(ax0, 0.f)) | ((unsigned)f2bf(fmaxf(ay0, 0.f)) << 16);
        *reinterpret_cast<unsigned*>(f + (size_t)n0 * 192 + g * 64 + fp) = pk0;
        if (has1) {
            unsigned pk1 = (unsigned)f2bf(fmaxf(ax1, 0.f)) | ((unsigned)f2bf(fmaxf(ay1, 0.f)) << 16);
            *reinterpret_cast<unsigned*>(f + (size_t)n1 * 192 + g * 64 + fp) = pk1;
        }
    }
}

// segment-pool bf16 f by sorted batch_idx; 32-row chunks for occupancy.
__global__ void pool_kernel(const unsigned short* __restrict__ f, const int* __restrict__ bidx,
                            int N, float* __restrict__ pooled) {
    const int c  = threadIdx.x;          // 0..191
    const int r0 = blockIdx.x * POOLROWS;
    const int r1 = min(r0 + POOLROWS, N);
    if (r0 >= N) return;
    float acc = 0.f;
    int cur = bidx[r0];
    for (int r = r0; r < r1; ++r) {
        int b = bidx[r];
        if (b != cur) {
            atomicAdd(&pooled[(size_t)cur * 192 + c], acc);
            acc = 0.f;
            cur = b;
        }
        acc += bf2f(f[(size_t)r * 192 + c]);
    }
    atomicAdd(&pooled[(size_t)cur * 192 + c], acc);
}

__global__ void mlp_kernel(const float* __restrict__ pooled,
                           const float* __restrict__ A1, const float* __restrict__ ba1,
                           const float* __restrict__ A2, const float* __restrict__ ba2,
                           float* __restrict__ out) {
    __shared__ float p[192];
    __shared__ float hid[256];
    const int b = blockIdx.x;
    const int t = threadIdx.x;
    if (t < 192) p[t] = pooled[(size_t)b * 192 + t];
    __syncthreads();
    float acc = ba1[t];
    for (int k = 0; k < 192; ++k) acc += p[k] * A1[(size_t)k * 256 + t];
    hid[t] = fmaxf(acc, 0.f);
    __syncthreads();
    if (t < 10) {
        float o = ba2[t];
        for (int k = 0; k < 256; ++k) o += hid[k] * A2[(size_t)k * 10 + t];
        out[(size_t)b * 10 + t] = o;
    }
}

extern "C" void kernel_launch(void* const* d_in, const int* in_sizes, int n_in,
                              void* d_out, int out_size, void* d_ws, size_t ws_size,
                              hipStream_t stream) {
    const float* x      = (const float*)d_in[0];
    const int*   map00  = (const int*)d_in[1];
    const int*   map01  = (const int*)d_in[2];
    const int*   map02  = (const int*)d_in[3];
    const int*   map10  = (const int*)d_in[4];
    const int*   map11  = (const int*)d_in[5];
    const int*   map12  = (const int*)d_in[6];
    const int*   bidx   = (const int*)d_in[7];
    const float* W00 = (const float*)d_in[9];  const float* b00 = (const float*)d_in[10];
    const float* W01 = (const float*)d_in[11]; const float* b01 = (const float*)d_in[12];
    const float* W02 = (const float*)d_in[13]; const float* b02 = (const float*)d_in[14];
    const float* W10 = (const float*)d_in[15]; const float* b10 = (const float*)d_in[16];
    const float* W11 = (const float*)d_in[17]; const float* b11 = (const float*)d_in[18];
    const float* W12 = (const float*)d_in[19]; const float* b12 = (const float*)d_in[20];
    const float* A1  = (const float*)d_in[21]; const float* ba1 = (const float*)d_in[22];
    const float* A2  = (const float*)d_in[23]; const float* ba2 = (const float*)d_in[24];

    const int N   = in_sizes[0] / 128;
    const int E   = in_sizes[1] / 2;
    const int NSB = (N + 511) >> SBSHIFT;      // 98 super-buckets of 512 nodes

    unsigned short* bufH = (unsigned short*)d_ws;                    // [N+1,192] bf16
    unsigned short* bufF = bufH + (size_t)(N + 1) * 192;             // [N,192] bf16
    float*    pooled = (float*)(bufF + (size_t)N * 192);             // [64,192] f32
    int*      cnt    = (int*)(pooled + 64 * 192);                    // 6*NSB
    unsigned* p1     = (unsigned*)(cnt + 6 * NSB);                   // 6*NSB*CAPSB
    unsigned short* cols = (unsigned short*)(p1 + (size_t)6 * NSB * CAPSB); // +32 slack
    int*      rows   = (int*)(cols + (size_t)6 * NSB * CAPCOL + 32); // 6*N
    unsigned short* wpack = (unsigned short*)(rows + (size_t)6 * N); // 6*12288 bf16

    dim3 gemmGrid((N + 63) / 64, 3);
    dim3 p1Grid((E + CHUNK - 1) / CHUNK, 6);
    dim3 sortGrid(NSB, 6);
    dim3 aggGrid((N + 7) / 8, 3);              // 4 waves/block x 2 nodes/wave

    // build CSR for all 6 maps + pack weights + zero cnt/pooled/h-dummy
    prepack_w<<<7, 256, 0, stream>>>(W00, W01, W02, W10, W11, W12, wpack,
                                     bufH, N, cnt, NSB, pooled);
    part_coarse<<<p1Grid, PTHREADS, 0, stream>>>(map00, map01, map02,
                                                 map10, map11, map12,
                                                 E, NSB, cnt, p1);
    sb_sort<<<sortGrid, PTHREADS, 0, stream>>>(NSB, N, cnt, p1, cols, rows);
    // layer 0
    gemm_mfma<0><<<gemmGrid, 256, 0, stream>>>(x, N, 128, wpack, b00, b01, b02, 0, bufH);
    csr_agg<<<aggGrid, 256, 0, stream>>>(bufH, rows, cols, N, NSB, 0, bufF);
    // layer 1
    gemm_mfma<1><<<gemmGrid, 256, 0, stream>>>(bufF, N, 192, wpack, b10, b11, b12, 3, bufH);
    csr_agg<<<aggGrid, 256, 0, stream>>>(bufH, rows, cols, N, NSB, 3, bufF);
    // pool + mlp
    pool_kernel<<<(N + POOLROWS - 1) / POOLROWS, 192, 0, stream>>>(bufF, bidx, N, pooled);
    mlp_kernel<<<64, 256, 0, stream>>>(pooled, A1, ba1, A2, ba2, (float*)d_out);
}